// Round 1
// baseline (1624.224 us; speedup 1.0000x reference)
//
#include <hip/hip_runtime.h>
#include <hip/hip_bf16.h>
#include <math.h>

#define G_CNT 4
#define U_CNT 100000
#define I_CNT 50000
#define N_ROWS (U_CNT + I_CNT)
#define D_DIM 64
#define T_STEPS 4
#define L_SEQ 50
#define B_CNT 2048
#define NPRED 8192
#define NS_CNT 4096
#define LEAKY_A 0.5f

#define TOWER_BLOCK 512
#define WAVES_PB (TOWER_BLOCK / 64)
#define ROWS_PW 4
#define ROWS_PB (WAVES_PB * ROWS_PW) // 32

__device__ __forceinline__ float bcast(float v, int srcLane) {
#if __has_builtin(__builtin_amdgcn_readlane)
    return __int_as_float(__builtin_amdgcn_readlane(__float_as_int(v), srcLane));
#else
    return __shfl(v, srcLane, 64);
#endif
}

__device__ __forceinline__ float waveReduceSum(float v) {
    v += __shfl_xor(v, 1, 64);
    v += __shfl_xor(v, 2, 64);
    v += __shfl_xor(v, 4, 64);
    v += __shfl_xor(v, 8, 64);
    v += __shfl_xor(v, 16, 64);
    v += __shfl_xor(v, 32, 64);
    return v;
}

__device__ __forceinline__ float reduce16(float v) {
    v += __shfl_xor(v, 1, 64);
    v += __shfl_xor(v, 2, 64);
    v += __shfl_xor(v, 4, 64);
    v += __shfl_xor(v, 8, 64);
    return v;
}

__device__ __forceinline__ float waveLayerNorm(float v) {
    float s  = waveReduceSum(v);
    float s2 = waveReduceSum(v * v);
    float mean = s * (1.0f / 64.0f);
    float var  = s2 * (1.0f / 64.0f) - mean * mean;
    return (v - mean) * rsqrtf(var + 1e-5f);
}

__device__ __forceinline__ float sigm(float x) { return 1.0f / (1.0f + __expf(-x)); }
__device__ __forceinline__ float tanh_(float x) {
    float xc = fminf(x, 15.0f);            // avoid inf/inf
    float t = __expf(2.0f * xc);
    return (t - 1.0f) / (t + 1.0f);
}
__device__ __forceinline__ float leakyf(float x) { return x >= 0.0f ? x : LEAKY_A * x; }

// ---------------------------------------------------------------------------
// Tower: LSTM(4 steps) + LN + 4-head MHSA + mean over T, for all U+I rows.
// One wave handles ROWS_PW rows; lane = feature dim.
// ---------------------------------------------------------------------------
__global__ __launch_bounds__(TOWER_BLOCK)
void tower_kernel(const float* __restrict__ uEmbed, const float* __restrict__ iEmbed,
                  const float* __restrict__ Wih, const float* __restrict__ Whh,
                  const float* __restrict__ bih, const float* __restrict__ bhh,
                  const float* __restrict__ Wq0, const float* __restrict__ Wk0, const float* __restrict__ Wv0,
                  const float* __restrict__ Wq1, const float* __restrict__ Wk1, const float* __restrict__ Wv1,
                  float* __restrict__ finalv)
{
    __shared__ float WT[128 * 256];   // WT[j][k]: j<64 -> Wih[k][j], j>=64 -> Whh[k][j-64]
    __shared__ float BS[256];

    const int tid = threadIdx.x;
    for (int idx = tid; idx < 64 * 256; idx += TOWER_BLOCK) {
        int k = idx >> 6, j = idx & 63;
        WT[j * 256 + k]        = Wih[idx];
        WT[(64 + j) * 256 + k] = Whh[idx];
    }
    if (tid < 256) BS[tid] = bih[tid] + bhh[tid];
    __syncthreads();

    const int lane = tid & 63;
    const int wave = tid >> 6;
    const int rowBase = blockIdx.x * ROWS_PB + wave * ROWS_PW;
    const bool isUser = rowBase < U_CNT;   // U_CNT % ROWS_PW == 0: wave-uniform

    const float* emb = isUser ? uEmbed : iEmbed;
    const int    cnt = isUser ? U_CNT : I_CNT;
    const int    rlocBase = isUser ? rowBase : (rowBase - U_CNT);

    float h[ROWS_PW], c[ROWS_PW];
    float ht[T_STEPS][ROWS_PW];
    bool  valid[ROWS_PW];
    int   rloc[ROWS_PW];
#pragma unroll
    for (int r = 0; r < ROWS_PW; ++r) {
        h[r] = 0.0f; c[r] = 0.0f;
        valid[r] = (rowBase + r) < N_ROWS;
        rloc[r]  = valid[r] ? (rlocBase + r) : 0;
    }

#pragma unroll
    for (int t = 0; t < T_STEPS; ++t) {
        float x[ROWS_PW];
#pragma unroll
        for (int r = 0; r < ROWS_PW; ++r)
            x[r] = 3.0f * emb[((size_t)t * cnt + rloc[r]) * D_DIM + lane];

        float a0[ROWS_PW], a1[ROWS_PW], a2[ROWS_PW], a3[ROWS_PW];
#pragma unroll
        for (int r = 0; r < ROWS_PW; ++r) {
            a0[r] = BS[lane]; a1[r] = BS[64 + lane];
            a2[r] = BS[128 + lane]; a3[r] = BS[192 + lane];
        }
        for (int j = 0; j < 64; ++j) {
            const float w0x = WT[j * 256 + lane];
            const float w1x = WT[j * 256 + 64 + lane];
            const float w2x = WT[j * 256 + 128 + lane];
            const float w3x = WT[j * 256 + 192 + lane];
            const float w0h = WT[(64 + j) * 256 + lane];
            const float w1h = WT[(64 + j) * 256 + 64 + lane];
            const float w2h = WT[(64 + j) * 256 + 128 + lane];
            const float w3h = WT[(64 + j) * 256 + 192 + lane];
#pragma unroll
            for (int r = 0; r < ROWS_PW; ++r) {
                float xj = bcast(x[r], j);
                float hj = bcast(h[r], j);
                a0[r] = fmaf(w0x, xj, fmaf(w0h, hj, a0[r]));
                a1[r] = fmaf(w1x, xj, fmaf(w1h, hj, a1[r]));
                a2[r] = fmaf(w2x, xj, fmaf(w2h, hj, a2[r]));
                a3[r] = fmaf(w3x, xj, fmaf(w3h, hj, a3[r]));
            }
        }
#pragma unroll
        for (int r = 0; r < ROWS_PW; ++r) {
            float ig = sigm(a0[r]), fg = sigm(a1[r]);
            float gg = tanh_(a2[r]), og = sigm(a3[r]);
            c[r] = fg * c[r] + ig * gg;
            h[r] = og * tanh_(c[r]);
            ht[t][r] = h[r];
        }
    }

    // layer norm each (t, r) over the 64 lanes
    float xn[T_STEPS][ROWS_PW];
#pragma unroll
    for (int t = 0; t < T_STEPS; ++t)
#pragma unroll
        for (int r = 0; r < ROWS_PW; ++r)
            xn[t][r] = waveLayerNorm(ht[t][r]);

    const float* WQ = isUser ? Wq0 : Wq1;
    const float* WK = isUser ? Wk0 : Wk1;
    const float* WV = isUser ? Wv0 : Wv1;

    float q[T_STEPS][ROWS_PW], k[T_STEPS][ROWS_PW], v[T_STEPS][ROWS_PW];
#pragma unroll
    for (int t = 0; t < T_STEPS; ++t)
#pragma unroll
        for (int r = 0; r < ROWS_PW; ++r) { q[t][r] = 0.f; k[t][r] = 0.f; v[t][r] = 0.f; }

    for (int j = 0; j < 64; ++j) {
        const float wq = WQ[j * 64 + lane];
        const float wk = WK[j * 64 + lane];
        const float wv = WV[j * 64 + lane];
#pragma unroll
        for (int t = 0; t < T_STEPS; ++t)
#pragma unroll
            for (int r = 0; r < ROWS_PW; ++r) {
                float b = bcast(xn[t][r], j);
                q[t][r] = fmaf(wq, b, q[t][r]);
                k[t][r] = fmaf(wk, b, k[t][r]);
                v[t][r] = fmaf(wv, b, v[t][r]);
            }
    }

    // attention per row: heads of 16 lanes, dk=16, scale 1/4; then mean over t
#pragma unroll
    for (int r = 0; r < ROWS_PW; ++r) {
        float sc[T_STEPS][T_STEPS];
#pragma unroll
        for (int t = 0; t < T_STEPS; ++t)
#pragma unroll
            for (int s = 0; s < T_STEPS; ++s) {
                float p = q[t][r] * k[s][r];
                sc[t][s] = reduce16(p) * 0.25f;
            }
        float outAcc = 0.0f;
#pragma unroll
        for (int t = 0; t < T_STEPS; ++t) {
            float mx = fmaxf(fmaxf(sc[t][0], sc[t][1]), fmaxf(sc[t][2], sc[t][3]));
            float e0 = __expf(sc[t][0] - mx), e1 = __expf(sc[t][1] - mx);
            float e2 = __expf(sc[t][2] - mx), e3 = __expf(sc[t][3] - mx);
            float inv = 1.0f / (e0 + e1 + e2 + e3);
            outAcc += (e0 * v[0][r] + e1 * v[1][r] + e2 * v[2][r] + e3 * v[3][r]) * inv;
        }
        if (valid[r])
            finalv[(size_t)(rowBase + r) * D_DIM + lane] = outAcc * 0.25f;
    }
}

// ---------------------------------------------------------------------------
// Sequence aggregation + 2 degenerate (T=1) attention layers -> att_user (B,64)
// ---------------------------------------------------------------------------
__global__ __launch_bounds__(256)
void seq_att_kernel(const float* __restrict__ finalv, const float* __restrict__ posEmbed,
                    const float* __restrict__ mask, const int* __restrict__ sequence,
                    const float* __restrict__ Wv_seq, float* __restrict__ att_user)
{
    const int lane = threadIdx.x & 63, wave = threadIdx.x >> 6;
    const int b = blockIdx.x * 4 + wave;
    if (b >= B_CNT) return;
    const float* fitem = finalv + (size_t)U_CNT * D_DIM;

    float acc = 0.0f;
    for (int l = 0; l < L_SEQ; ++l) {
        int   sid = sequence[b * L_SEQ + l];
        float m   = mask[b * L_SEQ + l];
        acc += m * (fitem[(size_t)sid * D_DIM + lane] + posEmbed[l * D_DIM + lane]);
    }
    float att = waveLayerNorm(acc);   // sb
#pragma unroll
    for (int layer = 0; layer < 2; ++layer) {
        float xnv = waveLayerNorm(att);
        float vv = 0.0f;
        const float* Wv = Wv_seq + layer * 64 * 64;
        for (int j = 0; j < 64; ++j)
            vv = fmaf(bcast(xnv, j), Wv[j * 64 + lane], vv);
        att = leakyf(vv) + att;
    }
    att_user[b * D_DIM + lane] = att;
}

// ---------------------------------------------------------------------------
// preds[n] = <fu[uids], fi[iids]> + <leaky(att_user[uLocs]), fi[iids]>
// ---------------------------------------------------------------------------
__global__ __launch_bounds__(256)
void preds_kernel(const float* __restrict__ finalv, const float* __restrict__ att_user,
                  const int* __restrict__ uids, const int* __restrict__ iids,
                  const int* __restrict__ uLocs, float* __restrict__ out)
{
    const int lane = threadIdx.x & 63, wave = threadIdx.x >> 6;
    const int n = blockIdx.x * 4 + wave;
    if (n >= NPRED) return;
    const int u = uids[n], it = iids[n], loc = uLocs[n];
    float fi = finalv[(size_t)(U_CNT + it) * D_DIM + lane];
    float fu = finalv[(size_t)u * D_DIM + lane];
    float au = leakyf(att_user[loc * D_DIM + lane]);
    float p = waveReduceSum(fu * fi + au * fi);
    if (lane == 0) out[n] = p;
}

// ---------------------------------------------------------------------------
// Per (g,s) sample: user_weight (meta MLP), S_final, p1
// ---------------------------------------------------------------------------
__global__ __launch_bounds__(256)
void pergs_kernel(const float* __restrict__ finalv,
                  const float* __restrict__ uEmbed, const float* __restrict__ iEmbed,
                  const int* __restrict__ suids, const int* __restrict__ siids,
                  const float* __restrict__ W2, const float* __restrict__ b2,
                  const float* __restrict__ W3, const float* __restrict__ b3,
                  float* __restrict__ uw, float* __restrict__ SfB, float* __restrict__ p1B)
{
    const int lane = threadIdx.x & 63, wave = threadIdx.x >> 6;
    const int idx = blockIdx.x * 4 + wave;        // 0 .. G*NS-1
    if (idx >= G_CNT * NS_CNT) return;
    const int g  = idx >> 12;                     // NS_CNT == 4096
    const int su = suids[idx], si = siids[idx];

    float fu = finalv[(size_t)su * D_DIM + lane];
    float fi = finalv[(size_t)(U_CNT + si) * D_DIM + lane];
    float uv = 3.0f * uEmbed[((size_t)g * U_CNT + su) * D_DIM + lane];
    float iv = 3.0f * iEmbed[((size_t)g * I_CNT + si) * D_DIM + lane];

    float sf = waveReduceSum(leakyf(fu * fi));
    float pp = waveReduceSum(leakyf(uv * iv));

    float m1a = fu * uv;
    float acc3 = 0.0f;
    for (int o = 0; o < 32; ++o) {
        float part = m1a * W2[o * 192 + lane]
                   + fu  * W2[o * 192 + 64 + lane]
                   + uv  * W2[o * 192 + 128 + lane];
        part = waveReduceSum(part);
        float m2 = leakyf(part + b2[o]);
        acc3 = fmaf(m2, W3[o], acc3);
    }
    float w = sigm(acc3 + b3[0]);
    if (lane == 0) { uw[idx] = w; SfB[idx] = sf; p1B[idx] = pp; }
}

// ---------------------------------------------------------------------------
// Final hinge loss, single block (deterministic)
// ---------------------------------------------------------------------------
__global__ __launch_bounds__(1024)
void ssl_kernel(const float* __restrict__ uw, const float* __restrict__ SfB,
                const float* __restrict__ p1B, float* __restrict__ out)
{
    const int tid = threadIdx.x;
    float local = 0.0f;
    for (int p = tid; p < G_CNT * 2048; p += 1024) {
        int g = p >> 11, s = p & 2047;
        int ip = g * NS_CNT + s, in_ = ip + 2048;
        float Sf   = uw[ip] * SfB[ip] - uw[in_] * SfB[in_];
        float diff = p1B[ip] - p1B[in_];
        local += fmaxf(1.0f - Sf * diff, 0.0f);
    }
    local = waveReduceSum(local);
    __shared__ float part[16];
    const int wave = tid >> 6, lane = tid & 63;
    if (lane == 0) part[wave] = local;
    __syncthreads();
    if (tid == 0) {
        float s = 0.0f;
        for (int i = 0; i < 16; ++i) s += part[i];
        out[NPRED] = s;
    }
}

extern "C" void kernel_launch(void* const* d_in, const int* in_sizes, int n_in,
                              void* d_out, int out_size, void* d_ws, size_t ws_size,
                              hipStream_t stream)
{
    const float* uEmbed  = (const float*)d_in[0];
    const float* iEmbed  = (const float*)d_in[1];
    const float* posEmbed= (const float*)d_in[2];
    const float* Wih     = (const float*)d_in[3];
    const float* Whh     = (const float*)d_in[4];
    const float* bih     = (const float*)d_in[5];
    const float* bhh     = (const float*)d_in[6];
    const float* Wq0     = (const float*)d_in[7];
    const float* Wk0     = (const float*)d_in[8];
    const float* Wv0     = (const float*)d_in[9];
    const float* Wq1     = (const float*)d_in[10];
    const float* Wk1     = (const float*)d_in[11];
    const float* Wv1     = (const float*)d_in[12];
    const float* Wv_seq  = (const float*)d_in[15];
    const float* meta2_W = (const float*)d_in[16];
    const float* meta2_b = (const float*)d_in[17];
    const float* meta3_W = (const float*)d_in[18];
    const float* meta3_b = (const float*)d_in[19];
    const float* mask    = (const float*)d_in[20];
    const int*   uids    = (const int*)d_in[21];
    const int*   iids    = (const int*)d_in[22];
    const int*   sequence= (const int*)d_in[23];
    const int*   uLocs   = (const int*)d_in[24];
    const int*   suids   = (const int*)d_in[25];
    const int*   siids   = (const int*)d_in[26];

    float* finalv   = (float*)d_ws;                       // N_ROWS*64
    float* att_user = finalv + (size_t)N_ROWS * D_DIM;    // B*64
    float* uwB      = att_user + (size_t)B_CNT * D_DIM;   // G*NS
    float* SfB      = uwB + (size_t)G_CNT * NS_CNT;
    float* p1B      = SfB + (size_t)G_CNT * NS_CNT;
    float* out      = (float*)d_out;

    const int towerGrid = (N_ROWS + ROWS_PB - 1) / ROWS_PB;
    tower_kernel<<<towerGrid, TOWER_BLOCK, 0, stream>>>(
        uEmbed, iEmbed, Wih, Whh, bih, bhh, Wq0, Wk0, Wv0, Wq1, Wk1, Wv1, finalv);

    seq_att_kernel<<<(B_CNT + 3) / 4, 256, 0, stream>>>(
        finalv, posEmbed, mask, sequence, Wv_seq, att_user);

    pergs_kernel<<<(G_CNT * NS_CNT) / 4, 256, 0, stream>>>(
        finalv, uEmbed, iEmbed, suids, siids, meta2_W, meta2_b, meta3_W, meta3_b,
        uwB, SfB, p1B);

    preds_kernel<<<NPRED / 4, 256, 0, stream>>>(finalv, att_user, uids, iids, uLocs, out);

    ssl_kernel<<<1, 1024, 0, stream>>>(uwB, SfB, p1B, out);
}

// Round 3
// 911.568 us; speedup vs baseline: 1.7818x; 1.7818x over previous
//
#include <hip/hip_runtime.h>
#include <hip/hip_bf16.h>
#include <math.h>

#define G_CNT 4
#define U_CNT 100000
#define I_CNT 50000
#define N_ROWS (U_CNT + I_CNT)
#define D_DIM 64
#define T_STEPS 4
#define L_SEQ 50
#define B_CNT 2048
#define NPRED 8192
#define NS_CNT 4096
#define LEAKY_A 0.5f

#define TOWER_BLOCK 512
#define WAVES_PB (TOWER_BLOCK / 64)
#define ROWS_PW 4
#define ROWS_PB (WAVES_PB * ROWS_PW) // 32

typedef _Float16 h2 __attribute__((ext_vector_type(2)));

__device__ __forceinline__ float bcast(float v, int srcLane) {
    return __int_as_float(__builtin_amdgcn_readlane(__float_as_int(v), srcLane));
}
__device__ __forceinline__ unsigned bcast_u(unsigned v, int srcLane) {
    return (unsigned)__builtin_amdgcn_readlane((int)v, srcLane);
}

__device__ __forceinline__ unsigned pkh2(float a, float b) {
    auto v = __builtin_amdgcn_cvt_pkrtz(a, b);   // __fp16 ext_vector_type(2)
    return __builtin_bit_cast(unsigned, v);
}

__device__ __forceinline__ float dot2(unsigned a, unsigned b, float c) {
#if __has_builtin(__builtin_amdgcn_fdot2)
    return __builtin_amdgcn_fdot2(__builtin_bit_cast(h2, a),
                                  __builtin_bit_cast(h2, b), c, false);
#else
    h2 av = __builtin_bit_cast(h2, a), bv = __builtin_bit_cast(h2, b);
    return c + (float)av.x * (float)bv.x + (float)av.y * (float)bv.y;
#endif
}

__device__ __forceinline__ float waveReduceSum(float v) {
    v += __shfl_xor(v, 1, 64);
    v += __shfl_xor(v, 2, 64);
    v += __shfl_xor(v, 4, 64);
    v += __shfl_xor(v, 8, 64);
    v += __shfl_xor(v, 16, 64);
    v += __shfl_xor(v, 32, 64);
    return v;
}

__device__ __forceinline__ float reduce16(float v) {
    v += __shfl_xor(v, 1, 64);
    v += __shfl_xor(v, 2, 64);
    v += __shfl_xor(v, 4, 64);
    v += __shfl_xor(v, 8, 64);
    return v;
}

__device__ __forceinline__ float waveLayerNorm(float v) {
    float s  = waveReduceSum(v);
    float s2 = waveReduceSum(v * v);
    float mean = s * (1.0f / 64.0f);
    float var  = s2 * (1.0f / 64.0f) - mean * mean;
    return (v - mean) * rsqrtf(var + 1e-5f);
}

__device__ __forceinline__ float sigm(float x) { return 1.0f / (1.0f + __expf(-x)); }
__device__ __forceinline__ float tanh_(float x) {
    float xc = fminf(x, 15.0f);
    float t = __expf(2.0f * xc);
    return (t - 1.0f) / (t + 1.0f);
}
__device__ __forceinline__ float leakyf(float x) { return x >= 0.0f ? x : LEAKY_A * x; }

// ---------------------------------------------------------------------------
// Tower: LSTM(4 steps) + LN + 4-head MHSA + mean over T, for all U+I rows.
// Weights as packed half2 (w_ih, w_hh) in LDS (64 KB -> 2 blocks/CU),
// XOR-swizzled column index so staging writes AND reads are conflict-free.
// Gate update: one v_dot2_f32_f16 per (gate, row) per j.
// ---------------------------------------------------------------------------
__global__ __launch_bounds__(TOWER_BLOCK, 4)
void tower_kernel(const float* __restrict__ uEmbed, const float* __restrict__ iEmbed,
                  const float* __restrict__ Wih, const float* __restrict__ Whh,
                  const float* __restrict__ bih, const float* __restrict__ bhh,
                  const float* __restrict__ Wq0, const float* __restrict__ Wk0, const float* __restrict__ Wv0,
                  const float* __restrict__ Wq1, const float* __restrict__ Wk1, const float* __restrict__ Wv1,
                  float* __restrict__ finalv)
{
    __shared__ unsigned WT2[64 * 256];  // [j][ (k ^ (j&31)) ] = half2(Wih[k][j], Whh[k][j])
    __shared__ float BS[256];

    const int tid = threadIdx.x;
    for (int idx = tid; idx < 64 * 256; idx += TOWER_BLOCK) {
        int k = idx >> 6, j = idx & 63;                 // global addr = k*64 + j = idx (coalesced)
        WT2[j * 256 + (k ^ (j & 31))] = pkh2(Wih[idx], Whh[idx]);
    }
    if (tid < 256) BS[tid] = bih[tid] + bhh[tid];
    __syncthreads();

    const int lane = tid & 63;
    const int wave = tid >> 6;
    const int rowBase = blockIdx.x * ROWS_PB + wave * ROWS_PW;
    const bool isUser = rowBase < U_CNT;   // U_CNT % ROWS_PW == 0: wave-uniform

    const float* emb = isUser ? uEmbed : iEmbed;
    const int    cnt = isUser ? U_CNT : I_CNT;
    const int    rlocBase = isUser ? rowBase : (rowBase - U_CNT);

    float h[ROWS_PW], c[ROWS_PW];
    float ht[T_STEPS][ROWS_PW];
    bool  valid[ROWS_PW];
    int   rloc[ROWS_PW];
#pragma unroll
    for (int r = 0; r < ROWS_PW; ++r) {
        h[r] = 0.0f; c[r] = 0.0f;
        valid[r] = (rowBase + r) < N_ROWS;
        rloc[r]  = valid[r] ? (rlocBase + r) : 0;
    }

#pragma unroll
    for (int t = 0; t < T_STEPS; ++t) {
        unsigned xh[ROWS_PW];
        float a0[ROWS_PW], a1[ROWS_PW], a2[ROWS_PW], a3[ROWS_PW];
#pragma unroll
        for (int r = 0; r < ROWS_PW; ++r) {
            float x = 3.0f * emb[((size_t)t * cnt + rloc[r]) * D_DIM + lane];
            xh[r] = pkh2(x, h[r]);
            a0[r] = BS[lane]; a1[r] = BS[64 + lane];
            a2[r] = BS[128 + lane]; a3[r] = BS[192 + lane];
        }
        for (int j = 0; j < 64; ++j) {
            const int sc = lane ^ (j & 31);             // swizzled low bits
            const unsigned w0 = WT2[j * 256 + sc];
            const unsigned w1 = WT2[j * 256 + (sc ^ 64)];
            const unsigned w2 = WT2[j * 256 + (sc ^ 128)];
            const unsigned w3 = WT2[j * 256 + (sc ^ 192)];
#pragma unroll
            for (int r = 0; r < ROWS_PW; ++r) {
                unsigned b = bcast_u(xh[r], j);
                a0[r] = dot2(w0, b, a0[r]);
                a1[r] = dot2(w1, b, a1[r]);
                a2[r] = dot2(w2, b, a2[r]);
                a3[r] = dot2(w3, b, a3[r]);
            }
        }
#pragma unroll
        for (int r = 0; r < ROWS_PW; ++r) {
            float ig = sigm(a0[r]), fg = sigm(a1[r]);
            float gg = tanh_(a2[r]), og = sigm(a3[r]);
            c[r] = fg * c[r] + ig * gg;
            h[r] = og * tanh_(c[r]);
            ht[t][r] = h[r];
        }
    }

    // layer norm each (t, r) over the 64 lanes, pack (xn_j, xn_{j+1}) pairs
    unsigned xnpk[T_STEPS][ROWS_PW];
#pragma unroll
    for (int t = 0; t < T_STEPS; ++t)
#pragma unroll
        for (int r = 0; r < ROWS_PW; ++r) {
            float xn = waveLayerNorm(ht[t][r]);
            float xn1 = __shfl_down(xn, 1, 64);
            xnpk[t][r] = pkh2(xn, xn1);                 // valid at even lanes
        }

    const float* WQ = isUser ? Wq0 : Wq1;
    const float* WK = isUser ? Wk0 : Wk1;
    const float* WV = isUser ? Wv0 : Wv1;

    float q[T_STEPS][ROWS_PW], k[T_STEPS][ROWS_PW], v[T_STEPS][ROWS_PW];
#pragma unroll
    for (int t = 0; t < T_STEPS; ++t)
#pragma unroll
        for (int r = 0; r < ROWS_PW; ++r) { q[t][r] = 0.f; k[t][r] = 0.f; v[t][r] = 0.f; }

    for (int jj = 0; jj < 64; jj += 2) {
        const unsigned wq = pkh2(WQ[jj * 64 + lane], WQ[(jj + 1) * 64 + lane]);
        const unsigned wk = pkh2(WK[jj * 64 + lane], WK[(jj + 1) * 64 + lane]);
        const unsigned wv = pkh2(WV[jj * 64 + lane], WV[(jj + 1) * 64 + lane]);
#pragma unroll
        for (int t = 0; t < T_STEPS; ++t)
#pragma unroll
            for (int r = 0; r < ROWS_PW; ++r) {
                unsigned b = bcast_u(xnpk[t][r], jj);
                q[t][r] = dot2(wq, b, q[t][r]);
                k[t][r] = dot2(wk, b, k[t][r]);
                v[t][r] = dot2(wv, b, v[t][r]);
            }
    }

    // attention per row: heads of 16 lanes, dk=16, scale 1/4; then mean over t
#pragma unroll
    for (int r = 0; r < ROWS_PW; ++r) {
        float sc[T_STEPS][T_STEPS];
#pragma unroll
        for (int t = 0; t < T_STEPS; ++t)
#pragma unroll
            for (int s = 0; s < T_STEPS; ++s) {
                float p = q[t][r] * k[s][r];
                sc[t][s] = reduce16(p) * 0.25f;
            }
        float outAcc = 0.0f;
#pragma unroll
        for (int t = 0; t < T_STEPS; ++t) {
            float mx = fmaxf(fmaxf(sc[t][0], sc[t][1]), fmaxf(sc[t][2], sc[t][3]));
            float e0 = __expf(sc[t][0] - mx), e1 = __expf(sc[t][1] - mx);
            float e2 = __expf(sc[t][2] - mx), e3 = __expf(sc[t][3] - mx);
            float inv = 1.0f / (e0 + e1 + e2 + e3);
            outAcc += (e0 * v[0][r] + e1 * v[1][r] + e2 * v[2][r] + e3 * v[3][r]) * inv;
        }
        if (valid[r])
            finalv[(size_t)(rowBase + r) * D_DIM + lane] = outAcc * 0.25f;
    }
}

// ---------------------------------------------------------------------------
// Sequence aggregation + 2 degenerate (T=1) attention layers -> att_user (B,64)
// ---------------------------------------------------------------------------
__global__ __launch_bounds__(256)
void seq_att_kernel(const float* __restrict__ finalv, const float* __restrict__ posEmbed,
                    const float* __restrict__ mask, const int* __restrict__ sequence,
                    const float* __restrict__ Wv_seq, float* __restrict__ att_user)
{
    const int lane = threadIdx.x & 63, wave = threadIdx.x >> 6;
    const int b = blockIdx.x * 4 + wave;
    if (b >= B_CNT) return;
    const float* fitem = finalv + (size_t)U_CNT * D_DIM;

    float acc = 0.0f;
    for (int l = 0; l < L_SEQ; ++l) {
        int   sid = sequence[b * L_SEQ + l];
        float m   = mask[b * L_SEQ + l];
        acc += m * (fitem[(size_t)sid * D_DIM + lane] + posEmbed[l * D_DIM + lane]);
    }
    float att = waveLayerNorm(acc);   // sb
#pragma unroll
    for (int layer = 0; layer < 2; ++layer) {
        float xnv = waveLayerNorm(att);
        float vv = 0.0f;
        const float* Wv = Wv_seq + layer * 64 * 64;
        for (int j = 0; j < 64; ++j)
            vv = fmaf(bcast(xnv, j), Wv[j * 64 + lane], vv);
        att = leakyf(vv) + att;
    }
    att_user[b * D_DIM + lane] = att;
}

// ---------------------------------------------------------------------------
// preds[n] = <fu[uids], fi[iids]> + <leaky(att_user[uLocs]), fi[iids]>
// ---------------------------------------------------------------------------
__global__ __launch_bounds__(256)
void preds_kernel(const float* __restrict__ finalv, const float* __restrict__ att_user,
                  const int* __restrict__ uids, const int* __restrict__ iids,
                  const int* __restrict__ uLocs, float* __restrict__ out)
{
    const int lane = threadIdx.x & 63, wave = threadIdx.x >> 6;
    const int n = blockIdx.x * 4 + wave;
    if (n >= NPRED) return;
    const int u = uids[n], it = iids[n], loc = uLocs[n];
    float fi = finalv[(size_t)(U_CNT + it) * D_DIM + lane];
    float fu = finalv[(size_t)u * D_DIM + lane];
    float au = leakyf(att_user[loc * D_DIM + lane]);
    float p = waveReduceSum(fu * fi + au * fi);
    if (lane == 0) out[n] = p;
}

// ---------------------------------------------------------------------------
// Per (g,s) sample: user_weight (meta MLP), S_final, p1
// ---------------------------------------------------------------------------
__global__ __launch_bounds__(256)
void pergs_kernel(const float* __restrict__ finalv,
                  const float* __restrict__ uEmbed, const float* __restrict__ iEmbed,
                  const int* __restrict__ suids, const int* __restrict__ siids,
                  const float* __restrict__ W2, const float* __restrict__ b2,
                  const float* __restrict__ W3, const float* __restrict__ b3,
                  float* __restrict__ uw, float* __restrict__ SfB, float* __restrict__ p1B)
{
    const int lane = threadIdx.x & 63, wave = threadIdx.x >> 6;
    const int idx = blockIdx.x * 4 + wave;        // 0 .. G*NS-1
    if (idx >= G_CNT * NS_CNT) return;
    const int g  = idx >> 12;                     // NS_CNT == 4096
    const int su = suids[idx], si = siids[idx];

    float fu = finalv[(size_t)su * D_DIM + lane];
    float fi = finalv[(size_t)(U_CNT + si) * D_DIM + lane];
    float uv = 3.0f * uEmbed[((size_t)g * U_CNT + su) * D_DIM + lane];
    float iv = 3.0f * iEmbed[((size_t)g * I_CNT + si) * D_DIM + lane];

    float sf = waveReduceSum(leakyf(fu * fi));
    float pp = waveReduceSum(leakyf(uv * iv));

    float m1a = fu * uv;
    float acc3 = 0.0f;
    for (int o = 0; o < 32; ++o) {
        float part = m1a * W2[o * 192 + lane]
                   + fu  * W2[o * 192 + 64 + lane]
                   + uv  * W2[o * 192 + 128 + lane];
        part = waveReduceSum(part);
        float m2 = leakyf(part + b2[o]);
        acc3 = fmaf(m2, W3[o], acc3);
    }
    float w = sigm(acc3 + b3[0]);
    if (lane == 0) { uw[idx] = w; SfB[idx] = sf; p1B[idx] = pp; }
}

// ---------------------------------------------------------------------------
// Final hinge loss, single block (deterministic)
// ---------------------------------------------------------------------------
__global__ __launch_bounds__(1024)
void ssl_kernel(const float* __restrict__ uw, const float* __restrict__ SfB,
                const float* __restrict__ p1B, float* __restrict__ out)
{
    const int tid = threadIdx.x;
    float local = 0.0f;
    for (int p = tid; p < G_CNT * 2048; p += 1024) {
        int g = p >> 11, s = p & 2047;
        int ip = g * NS_CNT + s, in_ = ip + 2048;
        float Sf   = uw[ip] * SfB[ip] - uw[in_] * SfB[in_];
        float diff = p1B[ip] - p1B[in_];
        local += fmaxf(1.0f - Sf * diff, 0.0f);
    }
    local = waveReduceSum(local);
    __shared__ float part[16];
    const int wave = tid >> 6, lane = tid & 63;
    if (lane == 0) part[wave] = local;
    __syncthreads();
    if (tid == 0) {
        float s = 0.0f;
        for (int i = 0; i < 16; ++i) s += part[i];
        out[NPRED] = s;
    }
}

extern "C" void kernel_launch(void* const* d_in, const int* in_sizes, int n_in,
                              void* d_out, int out_size, void* d_ws, size_t ws_size,
                              hipStream_t stream)
{
    const float* uEmbed  = (const float*)d_in[0];
    const float* iEmbed  = (const float*)d_in[1];
    const float* posEmbed= (const float*)d_in[2];
    const float* Wih     = (const float*)d_in[3];
    const float* Whh     = (const float*)d_in[4];
    const float* bih     = (const float*)d_in[5];
    const float* bhh     = (const float*)d_in[6];
    const float* Wq0     = (const float*)d_in[7];
    const float* Wk0     = (const float*)d_in[8];
    const float* Wv0     = (const float*)d_in[9];
    const float* Wq1     = (const float*)d_in[10];
    const float* Wk1     = (const float*)d_in[11];
    const float* Wv1     = (const float*)d_in[12];
    const float* Wv_seq  = (const float*)d_in[15];
    const float* meta2_W = (const float*)d_in[16];
    const float* meta2_b = (const float*)d_in[17];
    const float* meta3_W = (const float*)d_in[18];
    const float* meta3_b = (const float*)d_in[19];
    const float* mask    = (const float*)d_in[20];
    const int*   uids    = (const int*)d_in[21];
    const int*   iids    = (const int*)d_in[22];
    const int*   sequence= (const int*)d_in[23];
    const int*   uLocs   = (const int*)d_in[24];
    const int*   suids   = (const int*)d_in[25];
    const int*   siids   = (const int*)d_in[26];

    float* finalv   = (float*)d_ws;                       // N_ROWS*64
    float* att_user = finalv + (size_t)N_ROWS * D_DIM;    // B*64
    float* uwB      = att_user + (size_t)B_CNT * D_DIM;   // G*NS
    float* SfB      = uwB + (size_t)G_CNT * NS_CNT;
    float* p1B      = SfB + (size_t)G_CNT * NS_CNT;
    float* out      = (float*)d_out;

    const int towerGrid = (N_ROWS + ROWS_PB - 1) / ROWS_PB;
    tower_kernel<<<towerGrid, TOWER_BLOCK, 0, stream>>>(
        uEmbed, iEmbed, Wih, Whh, bih, bhh, Wq0, Wk0, Wv0, Wq1, Wk1, Wv1, finalv);

    seq_att_kernel<<<(B_CNT + 3) / 4, 256, 0, stream>>>(
        finalv, posEmbed, mask, sequence, Wv_seq, att_user);

    pergs_kernel<<<(G_CNT * NS_CNT) / 4, 256, 0, stream>>>(
        finalv, uEmbed, iEmbed, suids, siids, meta2_W, meta2_b, meta3_W, meta3_b,
        uwB, SfB, p1B);

    preds_kernel<<<NPRED / 4, 256, 0, stream>>>(finalv, att_user, uids, iids, uLocs, out);

    ssl_kernel<<<1, 1024, 0, stream>>>(uwB, SfB, p1B, out);
}

// Round 6
// 432.051 us; speedup vs baseline: 3.7593x; 2.1099x over previous
//
#include <hip/hip_runtime.h>
#include <hip/hip_bf16.h>
#include <math.h>

#define G_CNT 4
#define U_CNT 100000
#define I_CNT 50000
#define N_ROWS (U_CNT + I_CNT)
#define D_DIM 64
#define T_STEPS 4
#define L_SEQ 50
#define B_CNT 2048
#define NPRED 8192
#define NS_CNT 4096
#define LEAKY_A 0.5f

typedef short bf16x8 __attribute__((ext_vector_type(8)));
typedef float f32x4 __attribute__((ext_vector_type(4)));

union U16B { unsigned u[4]; bf16x8 v; };

// f32 -> bf16 RNE, pure C (no inline asm)
__device__ __forceinline__ unsigned bfr(float x) {
    unsigned u = __float_as_uint(x);
    return (u + 0x7fffu + ((u >> 16) & 1u)) >> 16;
}
__device__ __forceinline__ unsigned pkbf(float a, float b) {
    return bfr(a) | (bfr(b) << 16);
}
__device__ __forceinline__ float bf_lo(unsigned u) { return __uint_as_float(u << 16); }
__device__ __forceinline__ float bf_hi(unsigned u) { return __uint_as_float(u & 0xffff0000u); }

__device__ __forceinline__ float bcast(float v, int srcLane) {
    return __int_as_float(__builtin_amdgcn_readlane(__float_as_int(v), srcLane));
}

__device__ __forceinline__ float waveReduceSum(float v) {
    v += __shfl_xor(v, 1, 64);
    v += __shfl_xor(v, 2, 64);
    v += __shfl_xor(v, 4, 64);
    v += __shfl_xor(v, 8, 64);
    v += __shfl_xor(v, 16, 64);
    v += __shfl_xor(v, 32, 64);
    return v;
}

__device__ __forceinline__ float waveLayerNorm(float v) {
    float s  = waveReduceSum(v);
    float s2 = waveReduceSum(v * v);
    float mean = s * (1.0f / 64.0f);
    float var  = s2 * (1.0f / 64.0f) - mean * mean;
    return (v - mean) * rsqrtf(var + 1e-5f);
}

__device__ __forceinline__ float sigm(float x) { return 1.0f / (1.0f + __expf(-x)); }
__device__ __forceinline__ float tanh_(float x) {
    float xc = fminf(x, 15.0f);
    float t = __expf(2.0f * xc);
    return (t - 1.0f) / (t + 1.0f);
}
__device__ __forceinline__ float leakyf(float x) { return x >= 0.0f ? x : LEAKY_A * x; }

// ---------------------------------------------------------------------------
// MFMA tower: 8 waves/block, 16 rows/wave; grid = ceil(N_ROWS/128) = 1172.
// Last overhanging wave clamps its row base (loads valid rows, skips store).
// A = weights (M=16 gate-dims/tile x K), B = state (K x N=16 rows); identical
// (lanegroup,slot)->k map on both sides => k-order invariant.
// C/D: col(lane&15)=row, M=4*(lane>>4)+reg [m89-verified].
// ---------------------------------------------------------------------------
__global__ __launch_bounds__(512)
void tower_kernel(const float* __restrict__ uEmbed, const float* __restrict__ iEmbed,
                  const float* __restrict__ Wih, const float* __restrict__ Whh,
                  const float* __restrict__ bih, const float* __restrict__ bhh,
                  const float* __restrict__ Wq0, const float* __restrict__ Wk0, const float* __restrict__ Wv0,
                  const float* __restrict__ Wq1, const float* __restrict__ Wk1, const float* __restrict__ Wv1,
                  float* __restrict__ finalv)
{
    __shared__ char WFRAG[65536];   // LSTM: 64 frags (m*4+kc)*1024; later 48 QKV frags
    __shared__ float BSL[256];
    __shared__ char STG[16384];     // per-wave 2KB: 16 rows x 64 d bf16, 8B-unit XOR swizzle

    const int tid  = threadIdx.x;
    const int lane = tid & 63;
    const int wave = tid >> 6;
    const int r    = lane & 15;
    const int g    = lane >> 4;

    // ---- stage LSTM weight fragments (bf16) ----
#pragma unroll
    for (int i = 0; i < 8; ++i) {
        int f = wave * 8 + i;               // 0..63
        int m = f >> 2, kc = f & 3;
        int gate = m * 16 + r;
        int k0 = kc * 32 + 8 * g;
        const float* src = (k0 < 64) ? (Wih + gate * 64 + k0)
                                     : (Whh + gate * 64 + (k0 - 64));
        float4 lo = *(const float4*)src;
        float4 hi = *(const float4*)(src + 4);
        U16B u;
        u.u[0] = pkbf(lo.x, lo.y); u.u[1] = pkbf(lo.z, lo.w);
        u.u[2] = pkbf(hi.x, hi.y); u.u[3] = pkbf(hi.z, hi.w);
        *(bf16x8*)(WFRAG + f * 1024 + lane * 16) = u.v;
    }
    if (tid < 256) BSL[tid] = bih[tid] + bhh[tid];
    __syncthreads();

    const int rowBase0 = blockIdx.x * 128 + wave * 16;
    const bool active  = rowBase0 < N_ROWS;            // wave-uniform (16 | N_ROWS)
    const int rowBase  = active ? rowBase0 : (N_ROWS - 16);
    const bool isUser = rowBase < U_CNT;               // 16 | 100000 -> wave-uniform
    const float* emb = isUser ? uEmbed : iEmbed;
    const int cnt = isUser ? U_CNT : I_CNT;
    const int rloc = (isUser ? rowBase : rowBase - U_CNT) + r;

    // ---- x B-frags for all 4 steps (x3.0, bf16) ----
    bf16x8 xf[T_STEPS][2];
#pragma unroll
    for (int t = 0; t < 4; ++t)
#pragma unroll
        for (int c = 0; c < 2; ++c) {
            const float* p = emb + ((size_t)t * cnt + rloc) * 64 + c * 32 + 8 * g;
            float4 lo = *(const float4*)p;
            float4 hi = *(const float4*)(p + 4);
            U16B u;
            u.u[0] = pkbf(3.0f * lo.x, 3.0f * lo.y);
            u.u[1] = pkbf(3.0f * lo.z, 3.0f * lo.w);
            u.u[2] = pkbf(3.0f * hi.x, 3.0f * hi.y);
            u.u[3] = pkbf(3.0f * hi.z, 3.0f * hi.w);
            xf[t][c] = u.v;
        }

    // ---- LSTM ----
    char* stg = STG + wave * 2048;
    float cst[4][4];
    uint2 htp[4][4];                    // packed h_t per (t, mm)
#pragma unroll
    for (int mm = 0; mm < 4; ++mm)
#pragma unroll
        for (int rg = 0; rg < 4; ++rg) cst[mm][rg] = 0.0f;

#pragma unroll
    for (int t = 0; t < 4; ++t) {
        f32x4 acc[16];
#pragma unroll
        for (int m = 0; m < 16; ++m)
            acc[m] = *(const f32x4*)((const char*)BSL + m * 64 + g * 16);  // bias bcast
#pragma unroll
        for (int kc = 0; kc < 2; ++kc) {
#pragma unroll
            for (int m = 0; m < 16; ++m) {
                bf16x8 af = *(const bf16x8*)(WFRAG + (m * 4 + kc) * 1024 + lane * 16);
                acc[m] = __builtin_amdgcn_mfma_f32_16x16x32_bf16(af, xf[t][kc], acc[m], 0, 0, 0);
            }
        }
        if (t > 0) {
#pragma unroll
            for (int c = 0; c < 2; ++c) {
                int p0 = (8 * c + 2 * g) ^ r;
                int p1 = (8 * c + 2 * g + 1) ^ r;
                uint2 ua = *(const uint2*)(stg + r * 128 + (p0 << 3));
                uint2 ub = *(const uint2*)(stg + r * 128 + (p1 << 3));
                U16B u; u.u[0] = ua.x; u.u[1] = ua.y; u.u[2] = ub.x; u.u[3] = ub.y;
#pragma unroll
                for (int m = 0; m < 16; ++m) {
                    bf16x8 af = *(const bf16x8*)(WFRAG + (m * 4 + 2 + c) * 1024 + lane * 16);
                    acc[m] = __builtin_amdgcn_mfma_f32_16x16x32_bf16(af, u.v, acc[m], 0, 0, 0);
                }
            }
        }
        // elementwise gates; d = mm*16 + 4g + reg, gate m = type*4 + mm
#pragma unroll
        for (int mm = 0; mm < 4; ++mm) {
            float hv[4];
#pragma unroll
            for (int rg = 0; rg < 4; ++rg) {
                float iv = acc[mm][rg];
                float fv = acc[4 + mm][rg];
                float gv = acc[8 + mm][rg];
                float ov = acc[12 + mm][rg];
                float cc = sigm(fv) * cst[mm][rg] + sigm(iv) * tanh_(gv);
                cst[mm][rg] = cc;
                hv[rg] = sigm(ov) * tanh_(cc);
            }
            uint2 hp; hp.x = pkbf(hv[0], hv[1]); hp.y = pkbf(hv[2], hv[3]);
            htp[t][mm] = hp;
            if (t < 3)
                *(uint2*)(stg + r * 128 + (((mm * 4 + g) ^ r) << 3)) = hp;
        }
    }

    // ---- LayerNorm per (t,row) + build xn B-frags via stage buffer ----
    bf16x8 xnf[4][2];
#pragma unroll
    for (int t = 0; t < 4; ++t) {
        float hv[16];
#pragma unroll
        for (int mm = 0; mm < 4; ++mm) {
            uint2 hp = htp[t][mm];
            hv[mm * 4 + 0] = bf_lo(hp.x); hv[mm * 4 + 1] = bf_hi(hp.x);
            hv[mm * 4 + 2] = bf_lo(hp.y); hv[mm * 4 + 3] = bf_hi(hp.y);
        }
        float s = 0.f, s2 = 0.f;
#pragma unroll
        for (int i2 = 0; i2 < 16; ++i2) { s += hv[i2]; s2 += hv[i2] * hv[i2]; }
        s  += __shfl_xor(s, 16, 64);  s  += __shfl_xor(s, 32, 64);
        s2 += __shfl_xor(s2, 16, 64); s2 += __shfl_xor(s2, 32, 64);
        float mean = s * (1.f / 64.f);
        float var  = s2 * (1.f / 64.f) - mean * mean;
        float rs = rsqrtf(var + 1e-5f);
#pragma unroll
        for (int mm = 0; mm < 4; ++mm) {
            float x0 = (hv[mm * 4 + 0] - mean) * rs, x1 = (hv[mm * 4 + 1] - mean) * rs;
            float x2 = (hv[mm * 4 + 2] - mean) * rs, x3 = (hv[mm * 4 + 3] - mean) * rs;
            uint2 xp; xp.x = pkbf(x0, x1); xp.y = pkbf(x2, x3);
            *(uint2*)(stg + r * 128 + (((mm * 4 + g) ^ r) << 3)) = xp;
        }
#pragma unroll
        for (int c = 0; c < 2; ++c) {
            int p0 = (8 * c + 2 * g) ^ r, p1 = (8 * c + 2 * g + 1) ^ r;
            uint2 ua = *(const uint2*)(stg + r * 128 + (p0 << 3));
            uint2 ub = *(const uint2*)(stg + r * 128 + (p1 << 3));
            U16B u; u.u[0] = ua.x; u.u[1] = ua.y; u.u[2] = ub.x; u.u[3] = ub.y;
            xnf[t][c] = u.v;
        }
    }

    // ---- restage W region with 6 QKV matrices as A-frags ----
    __syncthreads();
#pragma unroll
    for (int i = 0; i < 6; ++i) {
        int f = 8 * i + wave;                   // mat6 = i, slot = wave = m*2+kc
        int m = (wave >> 1) & 3, kc = wave & 1;
        const float* WM = (i == 0) ? Wq0 : (i == 1) ? Wk0 : (i == 2) ? Wv0
                        : (i == 3) ? Wq1 : (i == 4) ? Wk1 : Wv1;
        int dp = m * 16 + r;
        int k0 = kc * 32 + 8 * g;
        float v0 = WM[(k0 + 0) * 64 + dp], v1 = WM[(k0 + 1) * 64 + dp];
        float v2 = WM[(k0 + 2) * 64 + dp], v3 = WM[(k0 + 3) * 64 + dp];
        float v4 = WM[(k0 + 4) * 64 + dp], v5 = WM[(k0 + 5) * 64 + dp];
        float v6 = WM[(k0 + 6) * 64 + dp], v7 = WM[(k0 + 7) * 64 + dp];
        U16B u;
        u.u[0] = pkbf(v0, v1); u.u[1] = pkbf(v2, v3);
        u.u[2] = pkbf(v4, v5); u.u[3] = pkbf(v6, v7);
        *(bf16x8*)(WFRAG + f * 1024 + lane * 16) = u.v;
    }
    __syncthreads();

    const int base3 = isUser ? 0 : 3;

    // ---- K and V via MFMA first (packed bf16: 32+32 regs) ----
    uint2 kpk[4][4], vpk[4][4];
#pragma unroll
    for (int t = 0; t < 4; ++t) {
#pragma unroll
        for (int m = 0; m < 4; ++m) {
            f32x4 ak = {0.f, 0.f, 0.f, 0.f};
            f32x4 av = {0.f, 0.f, 0.f, 0.f};
#pragma unroll
            for (int kc = 0; kc < 2; ++kc) {
                bf16x8 afk = *(const bf16x8*)(WFRAG + ((1 + base3) * 8 + m * 2 + kc) * 1024 + lane * 16);
                bf16x8 afv = *(const bf16x8*)(WFRAG + ((2 + base3) * 8 + m * 2 + kc) * 1024 + lane * 16);
                ak = __builtin_amdgcn_mfma_f32_16x16x32_bf16(afk, xnf[t][kc], ak, 0, 0, 0);
                av = __builtin_amdgcn_mfma_f32_16x16x32_bf16(afv, xnf[t][kc], av, 0, 0, 0);
            }
            uint2 pk; pk.x = pkbf(ak[0], ak[1]); pk.y = pkbf(ak[2], ak[3]);
            kpk[t][m] = pk;
            uint2 pv; pv.x = pkbf(av[0], av[1]); pv.y = pkbf(av[2], av[3]);
            vpk[t][m] = pv;
        }
    }

    // ---- per-t: Q (f32, never packed) + attention; head = m tile ----
    float outv[4][4];
#pragma unroll
    for (int mm = 0; mm < 4; ++mm)
#pragma unroll
        for (int rg = 0; rg < 4; ++rg) outv[mm][rg] = 0.f;

#pragma unroll
    for (int t = 0; t < 4; ++t) {
        float qv[4][4];
#pragma unroll
        for (int m = 0; m < 4; ++m) {
            f32x4 aq = {0.f, 0.f, 0.f, 0.f};
#pragma unroll
            for (int kc = 0; kc < 2; ++kc) {
                bf16x8 afq = *(const bf16x8*)(WFRAG + ((0 + base3) * 8 + m * 2 + kc) * 1024 + lane * 16);
                aq = __builtin_amdgcn_mfma_f32_16x16x32_bf16(afq, xnf[t][kc], aq, 0, 0, 0);
            }
            qv[m][0] = aq[0]; qv[m][1] = aq[1]; qv[m][2] = aq[2]; qv[m][3] = aq[3];
        }
        float sc[4][4];                 // [s][mm]
#pragma unroll
        for (int s5 = 0; s5 < 4; ++s5) {
#pragma unroll
            for (int mm = 0; mm < 4; ++mm) {
                uint2 p = kpk[s5][mm];
                float pr = qv[mm][0] * bf_lo(p.x) + qv[mm][1] * bf_hi(p.x)
                         + qv[mm][2] * bf_lo(p.y) + qv[mm][3] * bf_hi(p.y);
                pr += __shfl_xor(pr, 16, 64);
                pr += __shfl_xor(pr, 32, 64);
                sc[s5][mm] = pr * 0.25f;
            }
        }
#pragma unroll
        for (int mm = 0; mm < 4; ++mm) {
            float mx = fmaxf(fmaxf(sc[0][mm], sc[1][mm]), fmaxf(sc[2][mm], sc[3][mm]));
            float e0 = __expf(sc[0][mm] - mx), e1 = __expf(sc[1][mm] - mx);
            float e2 = __expf(sc[2][mm] - mx), e3 = __expf(sc[3][mm] - mx);
            float inv = 1.f / (e0 + e1 + e2 + e3);
            float a0 = e0 * inv, a1 = e1 * inv, a2 = e2 * inv, a3 = e3 * inv;
            uint2 p0 = vpk[0][mm], p1 = vpk[1][mm], p2 = vpk[2][mm], p3 = vpk[3][mm];
            outv[mm][0] += a0 * bf_lo(p0.x) + a1 * bf_lo(p1.x) + a2 * bf_lo(p2.x) + a3 * bf_lo(p3.x);
            outv[mm][1] += a0 * bf_hi(p0.x) + a1 * bf_hi(p1.x) + a2 * bf_hi(p2.x) + a3 * bf_hi(p3.x);
            outv[mm][2] += a0 * bf_lo(p0.y) + a1 * bf_lo(p1.y) + a2 * bf_lo(p2.y) + a3 * bf_lo(p3.y);
            outv[mm][3] += a0 * bf_hi(p0.y) + a1 * bf_hi(p1.y) + a2 * bf_hi(p2.y) + a3 * bf_hi(p3.y);
        }
    }

    if (active) {
        float* dst = finalv + (size_t)(rowBase + r) * 64;
#pragma unroll
        for (int mm = 0; mm < 4; ++mm)
#pragma unroll
            for (int rg = 0; rg < 4; ++rg)
                dst[mm * 16 + 4 * g + rg] = outv[mm][rg] * 0.25f;
    }
}

// ---------------------------------------------------------------------------
// Sequence aggregation + 2 degenerate (T=1) attention layers -> att_user (B,64)
// ---------------------------------------------------------------------------
__global__ __launch_bounds__(256)
void seq_att_kernel(const float* __restrict__ finalv, const float* __restrict__ posEmbed,
                    const float* __restrict__ mask, const int* __restrict__ sequence,
                    const float* __restrict__ Wv_seq, float* __restrict__ att_user)
{
    const int lane = threadIdx.x & 63, wave = threadIdx.x >> 6;
    const int b = blockIdx.x * 4 + wave;
    if (b >= B_CNT) return;
    const float* fitem = finalv + (size_t)U_CNT * D_DIM;

    float acc = 0.0f;
    for (int l = 0; l < L_SEQ; ++l) {
        int   sid = sequence[b * L_SEQ + l];
        float m   = mask[b * L_SEQ + l];
        acc += m * (fitem[(size_t)sid * D_DIM + lane] + posEmbed[l * D_DIM + lane]);
    }
    float att = waveLayerNorm(acc);   // sb
#pragma unroll
    for (int layer = 0; layer < 2; ++layer) {
        float xnv = waveLayerNorm(att);
        float vv = 0.0f;
        const float* Wv = Wv_seq + layer * 64 * 64;
        for (int j = 0; j < 64; ++j)
            vv = fmaf(bcast(xnv, j), Wv[j * 64 + lane], vv);
        att = leakyf(vv) + att;
    }
    att_user[b * D_DIM + lane] = att;
}

// ---------------------------------------------------------------------------
// preds[n] = <fu[uids], fi[iids]> + <leaky(att_user[uLocs]), fi[iids]>
// ---------------------------------------------------------------------------
__global__ __launch_bounds__(256)
void preds_kernel(const float* __restrict__ finalv, const float* __restrict__ att_user,
                  const int* __restrict__ uids, const int* __restrict__ iids,
                  const int* __restrict__ uLocs, float* __restrict__ out)
{
    const int lane = threadIdx.x & 63, wave = threadIdx.x >> 6;
    const int n = blockIdx.x * 4 + wave;
    if (n >= NPRED) return;
    const int u = uids[n], it = iids[n], loc = uLocs[n];
    float fi = finalv[(size_t)(U_CNT + it) * D_DIM + lane];
    float fu = finalv[(size_t)u * D_DIM + lane];
    float au = leakyf(att_user[loc * D_DIM + lane]);
    float p = waveReduceSum(fu * fi + au * fi);
    if (lane == 0) out[n] = p;
}

// ---------------------------------------------------------------------------
// Per (g,s) sample: user_weight (meta MLP), S_final, p1
// ---------------------------------------------------------------------------
__global__ __launch_bounds__(256)
void pergs_kernel(const float* __restrict__ finalv,
                  const float* __restrict__ uEmbed, const float* __restrict__ iEmbed,
                  const int* __restrict__ suids, const int* __restrict__ siids,
                  const float* __restrict__ W2, const float* __restrict__ b2,
                  const float* __restrict__ W3, const float* __restrict__ b3,
                  float* __restrict__ uw, float* __restrict__ SfB, float* __restrict__ p1B)
{
    const int lane = threadIdx.x & 63, wave = threadIdx.x >> 6;
    const int idx = blockIdx.x * 4 + wave;        // 0 .. G*NS-1
    if (idx >= G_CNT * NS_CNT) return;
    const int g  = idx >> 12;                     // NS_CNT == 4096
    const int su = suids[idx], si = siids[idx];

    float fu = finalv[(size_t)su * D_DIM + lane];
    float fi = finalv[(size_t)(U_CNT + si) * D_DIM + lane];
    float uv = 3.0f * uEmbed[((size_t)g * U_CNT + su) * D_DIM + lane];
    float iv = 3.0f * iEmbed[((size_t)g * I_CNT + si) * D_DIM + lane];

    float sf = waveReduceSum(leakyf(fu * fi));
    float pp = waveReduceSum(leakyf(uv * iv));

    float m1a = fu * uv;
    float acc3 = 0.0f;
    for (int o = 0; o < 32; ++o) {
        float part = m1a * W2[o * 192 + lane]
                   + fu  * W2[o * 192 + 64 + lane]
                   + uv  * W2[o * 192 + 128 + lane];
        part = waveReduceSum(part);
        float m2 = leakyf(part + b2[o]);
        acc3 = fmaf(m2, W3[o], acc3);
    }
    float w = sigm(acc3 + b3[0]);
    if (lane == 0) { uw[idx] = w; SfB[idx] = sf; p1B[idx] = pp; }
}

// ---------------------------------------------------------------------------
// Final hinge loss, single block (deterministic)
// ---------------------------------------------------------------------------
__global__ __launch_bounds__(1024)
void ssl_kernel(const float* __restrict__ uw, const float* __restrict__ SfB,
                const float* __restrict__ p1B, float* __restrict__ out)
{
    const int tid = threadIdx.x;
    float local = 0.0f;
    for (int p = tid; p < G_CNT * 2048; p += 1024) {
        int g = p >> 11, s = p & 2047;
        int ip = g * NS_CNT + s, in_ = ip + 2048;
        float Sf   = uw[ip] * SfB[ip] - uw[in_] * SfB[in_];
        float diff = p1B[ip] - p1B[in_];
        local += fmaxf(1.0f - Sf * diff, 0.0f);
    }
    local = waveReduceSum(local);
    __shared__ float part[16];
    const int wave = tid >> 6, lane = tid & 63;
    if (lane == 0) part[wave] = local;
    __syncthreads();
    if (tid == 0) {
        float s = 0.0f;
        for (int i = 0; i < 16; ++i) s += part[i];
        out[NPRED] = s;
    }
}

extern "C" void kernel_launch(void* const* d_in, const int* in_sizes, int n_in,
                              void* d_out, int out_size, void* d_ws, size_t ws_size,
                              hipStream_t stream)
{
    const float* uEmbed  = (const float*)d_in[0];
    const float* iEmbed  = (const float*)d_in[1];
    const float* posEmbed= (const float*)d_in[2];
    const float* Wih     = (const float*)d_in[3];
    const float* Whh     = (const float*)d_in[4];
    const float* bih     = (const float*)d_in[5];
    const float* bhh     = (const float*)d_in[6];
    const float* Wq0     = (const float*)d_in[7];
    const float* Wk0     = (const float*)d_in[8];
    const float* Wv0     = (const float*)d_in[9];
    const float* Wq1     = (const float*)d_in[10];
    const float* Wk1     = (const float*)d_in[11];
    const float* Wv1     = (const float*)d_in[12];
    const float* Wv_seq  = (const float*)d_in[15];
    const float* meta2_W = (const float*)d_in[16];
    const float* meta2_b = (const float*)d_in[17];
    const float* meta3_W = (const float*)d_in[18];
    const float* meta3_b = (const float*)d_in[19];
    const float* mask    = (const float*)d_in[20];
    const int*   uids    = (const int*)d_in[21];
    const int*   iids    = (const int*)d_in[22];
    const int*   sequence= (const int*)d_in[23];
    const int*   uLocs   = (const int*)d_in[24];
    const int*   suids   = (const int*)d_in[25];
    const int*   siids   = (const int*)d_in[26];

    float* finalv   = (float*)d_ws;                       // N_ROWS*64
    float* att_user = finalv + (size_t)N_ROWS * D_DIM;    // B*64
    float* uwB      = att_user + (size_t)B_CNT * D_DIM;   // G*NS
    float* SfB      = uwB + (size_t)G_CNT * NS_CNT;
    float* p1B      = SfB + (size_t)G_CNT * NS_CNT;
    float* out      = (float*)d_out;

    tower_kernel<<<(N_ROWS + 127) / 128, 512, 0, stream>>>(
        uEmbed, iEmbed, Wih, Whh, bih, bhh, Wq0, Wk0, Wv0, Wq1, Wk1, Wv1, finalv);

    seq_att_kernel<<<(B_CNT + 3) / 4, 256, 0, stream>>>(
        finalv, posEmbed, mask, sequence, Wv_seq, att_user);

    pergs_kernel<<<(G_CNT * NS_CNT) / 4, 256, 0, stream>>>(
        finalv, uEmbed, iEmbed, suids, siids, meta2_W, meta2_b, meta3_W, meta3_b,
        uwB, SfB, p1B);

    preds_kernel<<<NPRED / 4, 256, 0, stream>>>(finalv, att_user, uids, iids, uLocs, out);

    ssl_kernel<<<1, 1024, 0, stream>>>(uwB, SfB, p1B, out);
}

// Round 7
// 431.928 us; speedup vs baseline: 3.7604x; 1.0003x over previous
//
#include <hip/hip_runtime.h>
#include <hip/hip_bf16.h>
#include <math.h>

#define G_CNT 4
#define U_CNT 100000
#define I_CNT 50000
#define N_ROWS (U_CNT + I_CNT)
#define D_DIM 64
#define T_STEPS 4
#define L_SEQ 50
#define B_CNT 2048
#define NPRED 8192
#define NS_CNT 4096
#define LEAKY_A 0.5f

typedef short bf16x8 __attribute__((ext_vector_type(8)));
typedef float f32x4 __attribute__((ext_vector_type(4)));

union U16B { unsigned u[4]; bf16x8 v; };

// f32 -> bf16 RNE, pure C (no inline asm)
__device__ __forceinline__ unsigned bfr(float x) {
    unsigned u = __float_as_uint(x);
    return (u + 0x7fffu + ((u >> 16) & 1u)) >> 16;
}
__device__ __forceinline__ unsigned pkbf(float a, float b) {
    return bfr(a) | (bfr(b) << 16);
}
__device__ __forceinline__ float bf_lo(unsigned u) { return __uint_as_float(u << 16); }
__device__ __forceinline__ float bf_hi(unsigned u) { return __uint_as_float(u & 0xffff0000u); }

__device__ __forceinline__ float bcast(float v, int srcLane) {
    return __int_as_float(__builtin_amdgcn_readlane(__float_as_int(v), srcLane));
}

__device__ __forceinline__ float waveReduceSum(float v) {
    v += __shfl_xor(v, 1, 64);
    v += __shfl_xor(v, 2, 64);
    v += __shfl_xor(v, 4, 64);
    v += __shfl_xor(v, 8, 64);
    v += __shfl_xor(v, 16, 64);
    v += __shfl_xor(v, 32, 64);
    return v;
}

__device__ __forceinline__ float waveLayerNorm(float v) {
    float s  = waveReduceSum(v);
    float s2 = waveReduceSum(v * v);
    float mean = s * (1.0f / 64.0f);
    float var  = s2 * (1.0f / 64.0f) - mean * mean;
    return (v - mean) * rsqrtf(var + 1e-5f);
}

__device__ __forceinline__ float sigm(float x) { return 1.0f / (1.0f + __expf(-x)); }
__device__ __forceinline__ float tanh_(float x) {
    float xc = fminf(x, 15.0f);
    float t = __expf(2.0f * xc);
    return (t - 1.0f) / (t + 1.0f);
}
__device__ __forceinline__ float leakyf(float x) { return x >= 0.0f ? x : LEAKY_A * x; }

// ---------------------------------------------------------------------------
// MFMA tower: 8 waves/block, 16 rows/wave; grid = ceil(N_ROWS/128) = 1172.
// LDS 83KB -> 1 block/CU -> 2 waves/SIMD; launch_bounds(512,2) => 256-VGPR
// budget so the ~180-reg live set never spills (r6: 128-reg cap cost 750MB
// of scratch HBM traffic per dispatch).
// A = weights (M=16 gate-dims/tile x K), B = state (K x N=16 rows); identical
// (lanegroup,slot)->k map on both sides => k-order invariant.
// C/D: col(lane&15)=row, M=4*(lane>>4)+reg [m89-verified].
// ---------------------------------------------------------------------------
__global__ __launch_bounds__(512, 2)
void tower_kernel(const float* __restrict__ uEmbed, const float* __restrict__ iEmbed,
                  const float* __restrict__ Wih, const float* __restrict__ Whh,
                  const float* __restrict__ bih, const float* __restrict__ bhh,
                  const float* __restrict__ Wq0, const float* __restrict__ Wk0, const float* __restrict__ Wv0,
                  const float* __restrict__ Wq1, const float* __restrict__ Wk1, const float* __restrict__ Wv1,
                  float* __restrict__ finalv)
{
    __shared__ char WFRAG[65536];   // LSTM: 64 frags (m*4+kc)*1024; later 48 QKV frags
    __shared__ float BSL[256];
    __shared__ char STG[16384];     // per-wave 2KB: 16 rows x 64 d bf16, 8B-unit XOR swizzle

    const int tid  = threadIdx.x;
    const int lane = tid & 63;
    const int wave = tid >> 6;
    const int r    = lane & 15;
    const int g    = lane >> 4;

    // ---- stage LSTM weight fragments (bf16) ----
#pragma unroll
    for (int i = 0; i < 8; ++i) {
        int f = wave * 8 + i;               // 0..63
        int m = f >> 2, kc = f & 3;
        int gate = m * 16 + r;
        int k0 = kc * 32 + 8 * g;
        const float* src = (k0 < 64) ? (Wih + gate * 64 + k0)
                                     : (Whh + gate * 64 + (k0 - 64));
        float4 lo = *(const float4*)src;
        float4 hi = *(const float4*)(src + 4);
        U16B u;
        u.u[0] = pkbf(lo.x, lo.y); u.u[1] = pkbf(lo.z, lo.w);
        u.u[2] = pkbf(hi.x, hi.y); u.u[3] = pkbf(hi.z, hi.w);
        *(bf16x8*)(WFRAG + f * 1024 + lane * 16) = u.v;
    }
    if (tid < 256) BSL[tid] = bih[tid] + bhh[tid];
    __syncthreads();

    const int rowBase0 = blockIdx.x * 128 + wave * 16;
    const bool active  = rowBase0 < N_ROWS;            // wave-uniform (16 | N_ROWS)
    const int rowBase  = active ? rowBase0 : (N_ROWS - 16);
    const bool isUser = rowBase < U_CNT;               // 16 | 100000 -> wave-uniform
    const float* emb = isUser ? uEmbed : iEmbed;
    const int cnt = isUser ? U_CNT : I_CNT;
    const int rloc = (isUser ? rowBase : rowBase - U_CNT) + r;

    // ---- x B-frags for all 4 steps (x3.0, bf16) ----
    bf16x8 xf[T_STEPS][2];
#pragma unroll
    for (int t = 0; t < 4; ++t)
#pragma unroll
        for (int c = 0; c < 2; ++c) {
            const float* p = emb + ((size_t)t * cnt + rloc) * 64 + c * 32 + 8 * g;
            float4 lo = *(const float4*)p;
            float4 hi = *(const float4*)(p + 4);
            U16B u;
            u.u[0] = pkbf(3.0f * lo.x, 3.0f * lo.y);
            u.u[1] = pkbf(3.0f * lo.z, 3.0f * lo.w);
            u.u[2] = pkbf(3.0f * hi.x, 3.0f * hi.y);
            u.u[3] = pkbf(3.0f * hi.z, 3.0f * hi.w);
            xf[t][c] = u.v;
        }

    // ---- LSTM ----
    char* stg = STG + wave * 2048;
    float cst[4][4];
    uint2 htp[4][4];                    // packed h_t per (t, mm)
#pragma unroll
    for (int mm = 0; mm < 4; ++mm)
#pragma unroll
        for (int rg = 0; rg < 4; ++rg) cst[mm][rg] = 0.0f;

#pragma unroll
    for (int t = 0; t < 4; ++t) {
        f32x4 acc[16];
#pragma unroll
        for (int m = 0; m < 16; ++m)
            acc[m] = *(const f32x4*)((const char*)BSL + m * 64 + g * 16);  // bias bcast
#pragma unroll
        for (int kc = 0; kc < 2; ++kc) {
#pragma unroll
            for (int m = 0; m < 16; ++m) {
                bf16x8 af = *(const bf16x8*)(WFRAG + (m * 4 + kc) * 1024 + lane * 16);
                acc[m] = __builtin_amdgcn_mfma_f32_16x16x32_bf16(af, xf[t][kc], acc[m], 0, 0, 0);
            }
        }
        if (t > 0) {
#pragma unroll
            for (int c = 0; c < 2; ++c) {
                int p0 = (8 * c + 2 * g) ^ r;
                int p1 = (8 * c + 2 * g + 1) ^ r;
                uint2 ua = *(const uint2*)(stg + r * 128 + (p0 << 3));
                uint2 ub = *(const uint2*)(stg + r * 128 + (p1 << 3));
                U16B u; u.u[0] = ua.x; u.u[1] = ua.y; u.u[2] = ub.x; u.u[3] = ub.y;
#pragma unroll
                for (int m = 0; m < 16; ++m) {
                    bf16x8 af = *(const bf16x8*)(WFRAG + (m * 4 + 2 + c) * 1024 + lane * 16);
                    acc[m] = __builtin_amdgcn_mfma_f32_16x16x32_bf16(af, u.v, acc[m], 0, 0, 0);
                }
            }
        }
        // elementwise gates; d = mm*16 + 4g + reg, gate m = type*4 + mm
#pragma unroll
        for (int mm = 0; mm < 4; ++mm) {
            float hv[4];
#pragma unroll
            for (int rg = 0; rg < 4; ++rg) {
                float iv = acc[mm][rg];
                float fv = acc[4 + mm][rg];
                float gv = acc[8 + mm][rg];
                float ov = acc[12 + mm][rg];
                float cc = sigm(fv) * cst[mm][rg] + sigm(iv) * tanh_(gv);
                cst[mm][rg] = cc;
                hv[rg] = sigm(ov) * tanh_(cc);
            }
            uint2 hp; hp.x = pkbf(hv[0], hv[1]); hp.y = pkbf(hv[2], hv[3]);
            htp[t][mm] = hp;
            if (t < 3)
                *(uint2*)(stg + r * 128 + (((mm * 4 + g) ^ r) << 3)) = hp;
        }
    }

    // ---- LayerNorm per (t,row) + build xn B-frags via stage buffer ----
    bf16x8 xnf[4][2];
#pragma unroll
    for (int t = 0; t < 4; ++t) {
        float hv[16];
#pragma unroll
        for (int mm = 0; mm < 4; ++mm) {
            uint2 hp = htp[t][mm];
            hv[mm * 4 + 0] = bf_lo(hp.x); hv[mm * 4 + 1] = bf_hi(hp.x);
            hv[mm * 4 + 2] = bf_lo(hp.y); hv[mm * 4 + 3] = bf_hi(hp.y);
        }
        float s = 0.f, s2 = 0.f;
#pragma unroll
        for (int i2 = 0; i2 < 16; ++i2) { s += hv[i2]; s2 += hv[i2] * hv[i2]; }
        s  += __shfl_xor(s, 16, 64);  s  += __shfl_xor(s, 32, 64);
        s2 += __shfl_xor(s2, 16, 64); s2 += __shfl_xor(s2, 32, 64);
        float mean = s * (1.f / 64.f);
        float var  = s2 * (1.f / 64.f) - mean * mean;
        float rs = rsqrtf(var + 1e-5f);
#pragma unroll
        for (int mm = 0; mm < 4; ++mm) {
            float x0 = (hv[mm * 4 + 0] - mean) * rs, x1 = (hv[mm * 4 + 1] - mean) * rs;
            float x2 = (hv[mm * 4 + 2] - mean) * rs, x3 = (hv[mm * 4 + 3] - mean) * rs;
            uint2 xp; xp.x = pkbf(x0, x1); xp.y = pkbf(x2, x3);
            *(uint2*)(stg + r * 128 + (((mm * 4 + g) ^ r) << 3)) = xp;
        }
#pragma unroll
        for (int c = 0; c < 2; ++c) {
            int p0 = (8 * c + 2 * g) ^ r, p1 = (8 * c + 2 * g + 1) ^ r;
            uint2 ua = *(const uint2*)(stg + r * 128 + (p0 << 3));
            uint2 ub = *(const uint2*)(stg + r * 128 + (p1 << 3));
            U16B u; u.u[0] = ua.x; u.u[1] = ua.y; u.u[2] = ub.x; u.u[3] = ub.y;
            xnf[t][c] = u.v;
        }
    }

    // ---- restage W region with 6 QKV matrices as A-frags ----
    __syncthreads();
#pragma unroll
    for (int i = 0; i < 6; ++i) {
        int f = 8 * i + wave;                   // mat6 = i, slot = wave = m*2+kc
        int m = (wave >> 1) & 3, kc = wave & 1;
        const float* WM = (i == 0) ? Wq0 : (i == 1) ? Wk0 : (i == 2) ? Wv0
                        : (i == 3) ? Wq1 : (i == 4) ? Wk1 : Wv1;
        int dp = m * 16 + r;
        int k0 = kc * 32 + 8 * g;
        float v0 = WM[(k0 + 0) * 64 + dp], v1 = WM[(k0 + 1) * 64 + dp];
        float v2 = WM[(k0 + 2) * 64 + dp], v3 = WM[(k0 + 3) * 64 + dp];
        float v4 = WM[(k0 + 4) * 64 + dp], v5 = WM[(k0 + 5) * 64 + dp];
        float v6 = WM[(k0 + 6) * 64 + dp], v7 = WM[(k0 + 7) * 64 + dp];
        U16B u;
        u.u[0] = pkbf(v0, v1); u.u[1] = pkbf(v2, v3);
        u.u[2] = pkbf(v4, v5); u.u[3] = pkbf(v6, v7);
        *(bf16x8*)(WFRAG + f * 1024 + lane * 16) = u.v;
    }
    __syncthreads();

    const int base3 = isUser ? 0 : 3;

    // ---- K and V via MFMA first (packed bf16: 32+32 regs) ----
    uint2 kpk[4][4], vpk[4][4];
#pragma unroll
    for (int t = 0; t < 4; ++t) {
#pragma unroll
        for (int m = 0; m < 4; ++m) {
            f32x4 ak = {0.f, 0.f, 0.f, 0.f};
            f32x4 av = {0.f, 0.f, 0.f, 0.f};
#pragma unroll
            for (int kc = 0; kc < 2; ++kc) {
                bf16x8 afk = *(const bf16x8*)(WFRAG + ((1 + base3) * 8 + m * 2 + kc) * 1024 + lane * 16);
                bf16x8 afv = *(const bf16x8*)(WFRAG + ((2 + base3) * 8 + m * 2 + kc) * 1024 + lane * 16);
                ak = __builtin_amdgcn_mfma_f32_16x16x32_bf16(afk, xnf[t][kc], ak, 0, 0, 0);
                av = __builtin_amdgcn_mfma_f32_16x16x32_bf16(afv, xnf[t][kc], av, 0, 0, 0);
            }
            uint2 pk; pk.x = pkbf(ak[0], ak[1]); pk.y = pkbf(ak[2], ak[3]);
            kpk[t][m] = pk;
            uint2 pv; pv.x = pkbf(av[0], av[1]); pv.y = pkbf(av[2], av[3]);
            vpk[t][m] = pv;
        }
    }

    // ---- per-t: Q (f32, never packed) + attention; head = m tile ----
    float outv[4][4];
#pragma unroll
    for (int mm = 0; mm < 4; ++mm)
#pragma unroll
        for (int rg = 0; rg < 4; ++rg) outv[mm][rg] = 0.f;

#pragma unroll
    for (int t = 0; t < 4; ++t) {
        float qv[4][4];
#pragma unroll
        for (int m = 0; m < 4; ++m) {
            f32x4 aq = {0.f, 0.f, 0.f, 0.f};
#pragma unroll
            for (int kc = 0; kc < 2; ++kc) {
                bf16x8 afq = *(const bf16x8*)(WFRAG + ((0 + base3) * 8 + m * 2 + kc) * 1024 + lane * 16);
                aq = __builtin_amdgcn_mfma_f32_16x16x32_bf16(afq, xnf[t][kc], aq, 0, 0, 0);
            }
            qv[m][0] = aq[0]; qv[m][1] = aq[1]; qv[m][2] = aq[2]; qv[m][3] = aq[3];
        }
        float sc[4][4];                 // [s][mm]
#pragma unroll
        for (int s5 = 0; s5 < 4; ++s5) {
#pragma unroll
            for (int mm = 0; mm < 4; ++mm) {
                uint2 p = kpk[s5][mm];
                float pr = qv[mm][0] * bf_lo(p.x) + qv[mm][1] * bf_hi(p.x)
                         + qv[mm][2] * bf_lo(p.y) + qv[mm][3] * bf_hi(p.y);
                pr += __shfl_xor(pr, 16, 64);
                pr += __shfl_xor(pr, 32, 64);
                sc[s5][mm] = pr * 0.25f;
            }
        }
#pragma unroll
        for (int mm = 0; mm < 4; ++mm) {
            float mx = fmaxf(fmaxf(sc[0][mm], sc[1][mm]), fmaxf(sc[2][mm], sc[3][mm]));
            float e0 = __expf(sc[0][mm] - mx), e1 = __expf(sc[1][mm] - mx);
            float e2 = __expf(sc[2][mm] - mx), e3 = __expf(sc[3][mm] - mx);
            float inv = 1.f / (e0 + e1 + e2 + e3);
            float a0 = e0 * inv, a1 = e1 * inv, a2 = e2 * inv, a3 = e3 * inv;
            uint2 p0 = vpk[0][mm], p1 = vpk[1][mm], p2 = vpk[2][mm], p3 = vpk[3][mm];
            outv[mm][0] += a0 * bf_lo(p0.x) + a1 * bf_lo(p1.x) + a2 * bf_lo(p2.x) + a3 * bf_lo(p3.x);
            outv[mm][1] += a0 * bf_hi(p0.x) + a1 * bf_hi(p1.x) + a2 * bf_hi(p2.x) + a3 * bf_hi(p3.x);
            outv[mm][2] += a0 * bf_lo(p0.y) + a1 * bf_lo(p1.y) + a2 * bf_lo(p2.y) + a3 * bf_lo(p3.y);
            outv[mm][3] += a0 * bf_hi(p0.y) + a1 * bf_hi(p1.y) + a2 * bf_hi(p2.y) + a3 * bf_hi(p3.y);
        }
    }

    if (active) {
        float* dst = finalv + (size_t)(rowBase + r) * 64;
#pragma unroll
        for (int mm = 0; mm < 4; ++mm) {
            float4 o4 = { outv[mm][0] * 0.25f, outv[mm][1] * 0.25f,
                          outv[mm][2] * 0.25f, outv[mm][3] * 0.25f };
            *(float4*)(dst + mm * 16 + 4 * g) = o4;
        }
    }
}

// ---------------------------------------------------------------------------
// Sequence aggregation + 2 degenerate (T=1) attention layers -> att_user (B,64)
// ---------------------------------------------------------------------------
__global__ __launch_bounds__(256)
void seq_att_kernel(const float* __restrict__ finalv, const float* __restrict__ posEmbed,
                    const float* __restrict__ mask, const int* __restrict__ sequence,
                    const float* __restrict__ Wv_seq, float* __restrict__ att_user)
{
    const int lane = threadIdx.x & 63, wave = threadIdx.x >> 6;
    const int b = blockIdx.x * 4 + wave;
    if (b >= B_CNT) return;
    const float* fitem = finalv + (size_t)U_CNT * D_DIM;

    float acc = 0.0f;
    for (int l = 0; l < L_SEQ; ++l) {
        int   sid = sequence[b * L_SEQ + l];
        float m   = mask[b * L_SEQ + l];
        acc += m * (fitem[(size_t)sid * D_DIM + lane] + posEmbed[l * D_DIM + lane]);
    }
    float att = waveLayerNorm(acc);   // sb
#pragma unroll
    for (int layer = 0; layer < 2; ++layer) {
        float xnv = waveLayerNorm(att);
        float vv = 0.0f;
        const float* Wv = Wv_seq + layer * 64 * 64;
        for (int j = 0; j < 64; ++j)
            vv = fmaf(bcast(xnv, j), Wv[j * 64 + lane], vv);
        att = leakyf(vv) + att;
    }
    att_user[b * D_DIM + lane] = att;
}

// ---------------------------------------------------------------------------
// preds[n] = <fu[uids], fi[iids]> + <leaky(att_user[uLocs]), fi[iids]>
// ---------------------------------------------------------------------------
__global__ __launch_bounds__(256)
void preds_kernel(const float* __restrict__ finalv, const float* __restrict__ att_user,
                  const int* __restrict__ uids, const int* __restrict__ iids,
                  const int* __restrict__ uLocs, float* __restrict__ out)
{
    const int lane = threadIdx.x & 63, wave = threadIdx.x >> 6;
    const int n = blockIdx.x * 4 + wave;
    if (n >= NPRED) return;
    const int u = uids[n], it = iids[n], loc = uLocs[n];
    float fi = finalv[(size_t)(U_CNT + it) * D_DIM + lane];
    float fu = finalv[(size_t)u * D_DIM + lane];
    float au = leakyf(att_user[loc * D_DIM + lane]);
    float p = waveReduceSum(fu * fi + au * fi);
    if (lane == 0) out[n] = p;
}

// ---------------------------------------------------------------------------
// Per (g,s) sample: user_weight (meta MLP), S_final, p1
// ---------------------------------------------------------------------------
__global__ __launch_bounds__(256)
void pergs_kernel(const float* __restrict__ finalv,
                  const float* __restrict__ uEmbed, const float* __restrict__ iEmbed,
                  const int* __restrict__ suids, const int* __restrict__ siids,
                  const float* __restrict__ W2, const float* __restrict__ b2,
                  const float* __restrict__ W3, const float* __restrict__ b3,
                  float* __restrict__ uw, float* __restrict__ SfB, float* __restrict__ p1B)
{
    const int lane = threadIdx.x & 63, wave = threadIdx.x >> 6;
    const int idx = blockIdx.x * 4 + wave;        // 0 .. G*NS-1
    if (idx >= G_CNT * NS_CNT) return;
    const int g  = idx >> 12;                     // NS_CNT == 4096
    const int su = suids[idx], si = siids[idx];

    float fu = finalv[(size_t)su * D_DIM + lane];
    float fi = finalv[(size_t)(U_CNT + si) * D_DIM + lane];
    float uv = 3.0f * uEmbed[((size_t)g * U_CNT + su) * D_DIM + lane];
    float iv = 3.0f * iEmbed[((size_t)g * I_CNT + si) * D_DIM + lane];

    float sf = waveReduceSum(leakyf(fu * fi));
    float pp = waveReduceSum(leakyf(uv * iv));

    float m1a = fu * uv;
    float acc3 = 0.0f;
    for (int o = 0; o < 32; ++o) {
        float part = m1a * W2[o * 192 + lane]
                   + fu  * W2[o * 192 + 64 + lane]
                   + uv  * W2[o * 192 + 128 + lane];
        part = waveReduceSum(part);
        float m2 = leakyf(part + b2[o]);
        acc3 = fmaf(m2, W3[o], acc3);
    }
    float w = sigm(acc3 + b3[0]);
    if (lane == 0) { uw[idx] = w; SfB[idx] = sf; p1B[idx] = pp; }
}

// ---------------------------------------------------------------------------
// Final hinge loss, single block (deterministic)
// ---------------------------------------------------------------------------
__global__ __launch_bounds__(1024)
void ssl_kernel(const float* __restrict__ uw, const float* __restrict__ SfB,
                const float* __restrict__ p1B, float* __restrict__ out)
{
    const int tid = threadIdx.x;
    float local = 0.0f;
    for (int p = tid; p < G_CNT * 2048; p += 1024) {
        int g = p >> 11, s = p & 2047;
        int ip = g * NS_CNT + s, in_ = ip + 2048;
        float Sf   = uw[ip] * SfB[ip] - uw[in_] * SfB[in_];
        float diff = p1B[ip] - p1B[in_];
        local += fmaxf(1.0f - Sf * diff, 0.0f);
    }
    local = waveReduceSum(local);
    __shared__ float part[16];
    const int wave = tid >> 6, lane = tid & 63;
    if (lane == 0) part[wave] = local;
    __syncthreads();
    if (tid == 0) {
        float s = 0.0f;
        for (int i = 0; i < 16; ++i) s += part[i];
        out[NPRED] = s;
    }
}

extern "C" void kernel_launch(void* const* d_in, const int* in_sizes, int n_in,
                              void* d_out, int out_size, void* d_ws, size_t ws_size,
                              hipStream_t stream)
{
    const float* uEmbed  = (const float*)d_in[0];
    const float* iEmbed  = (const float*)d_in[1];
    const float* posEmbed= (const float*)d_in[2];
    const float* Wih     = (const float*)d_in[3];
    const float* Whh     = (const float*)d_in[4];
    const float* bih     = (const float*)d_in[5];
    const float* bhh     = (const float*)d_in[6];
    const float* Wq0     = (const float*)d_in[7];
    const float* Wk0     = (const float*)d_in[8];
    const float* Wv0     = (const float*)d_in[9];
    const float* Wq1     = (const float*)d_in[10];
    const float* Wk1     = (const float*)d_in[11];
    const float* Wv1     = (const float*)d_in[12];
    const float* Wv_seq  = (const float*)d_in[15];
    const float* meta2_W = (const float*)d_in[16];
    const float* meta2_b = (const float*)d_in[17];
    const float* meta3_W = (const float*)d_in[18];
    const float* meta3_b = (const float*)d_in[19];
    const float* mask    = (const float*)d_in[20];
    const int*   uids    = (const int*)d_in[21];
    const int*   iids    = (const int*)d_in[22];
    const int*   sequence= (const int*)d_in[23];
    const int*   uLocs   = (const int*)d_in[24];
    const int*   suids   = (const int*)d_in[25];
    const int*   siids   = (const int*)d_in[26];

    float* finalv   = (float*)d_ws;                       // N_ROWS*64
    float* att_user = finalv + (size_t)N_ROWS * D_DIM;    // B*64
    float* uwB      = att_user + (size_t)B_CNT * D_DIM;   // G*NS
    float* SfB      = uwB + (size_t)G_CNT * NS_CNT;
    float* p1B      = SfB + (size_t)G_CNT * NS_CNT;
    float* out      = (float*)d_out;

    tower_kernel<<<(N_ROWS + 127) / 128, 512, 0, stream>>>(
        uEmbed, iEmbed, Wih, Whh, bih, bhh, Wq0, Wk0, Wv0, Wq1, Wk1, Wv1, finalv);

    seq_att_kernel<<<(B_CNT + 3) / 4, 256, 0, stream>>>(
        finalv, posEmbed, mask, sequence, Wv_seq, att_user);

    pergs_kernel<<<(G_CNT * NS_CNT) / 4, 256, 0, stream>>>(
        finalv, uEmbed, iEmbed, suids, siids, meta2_W, meta2_b, meta3_W, meta3_b,
        uwB, SfB, p1B);

    preds_kernel<<<NPRED / 4, 256, 0, stream>>>(finalv, att_user, uids, iids, uLocs, out);

    ssl_kernel<<<1, 1024, 0, stream>>>(uwB, SfB, p1B, out);
}

// Round 8
// 393.512 us; speedup vs baseline: 4.1275x; 1.0976x over previous
//
#include <hip/hip_runtime.h>
#include <hip/hip_bf16.h>
#include <math.h>

#define G_CNT 4
#define U_CNT 100000
#define I_CNT 50000
#define N_ROWS (U_CNT + I_CNT)
#define D_DIM 64
#define T_STEPS 4
#define L_SEQ 50
#define B_CNT 2048
#define NPRED 8192
#define NS_CNT 4096
#define LEAKY_A 0.5f

typedef short bf16x8 __attribute__((ext_vector_type(8)));
typedef float f32x4 __attribute__((ext_vector_type(4)));

union U16B { unsigned u[4]; bf16x8 v; };

// f32 -> bf16 RNE, pure C (no inline asm)
__device__ __forceinline__ unsigned bfr(float x) {
    unsigned u = __float_as_uint(x);
    return (u + 0x7fffu + ((u >> 16) & 1u)) >> 16;
}
__device__ __forceinline__ unsigned pkbf(float a, float b) {
    return bfr(a) | (bfr(b) << 16);
}
__device__ __forceinline__ float bf_lo(unsigned u) { return __uint_as_float(u << 16); }
__device__ __forceinline__ float bf_hi(unsigned u) { return __uint_as_float(u & 0xffff0000u); }

__device__ __forceinline__ float bcast(float v, int srcLane) {
    return __int_as_float(__builtin_amdgcn_readlane(__float_as_int(v), srcLane));
}

__device__ __forceinline__ float waveReduceSum(float v) {
    v += __shfl_xor(v, 1, 64);
    v += __shfl_xor(v, 2, 64);
    v += __shfl_xor(v, 4, 64);
    v += __shfl_xor(v, 8, 64);
    v += __shfl_xor(v, 16, 64);
    v += __shfl_xor(v, 32, 64);
    return v;
}

__device__ __forceinline__ float waveLayerNorm(float v) {
    float s  = waveReduceSum(v);
    float s2 = waveReduceSum(v * v);
    float mean = s * (1.0f / 64.0f);
    float var  = s2 * (1.0f / 64.0f) - mean * mean;
    return (v - mean) * rsqrtf(var + 1e-5f);
}

__device__ __forceinline__ float sigm(float x) { return 1.0f / (1.0f + __expf(-x)); }
__device__ __forceinline__ float tanh_(float x) {
    float xc = fminf(x, 15.0f);
    float t = __expf(2.0f * xc);
    return (t - 1.0f) / (t + 1.0f);
}
__device__ __forceinline__ float leakyf(float x) { return x >= 0.0f ? x : LEAKY_A * x; }

// ---------------------------------------------------------------------------
// MFMA tower: 8 waves/block, 16 rows/wave; grid = ceil(N_ROWS/128) = 1172.
// LDS 97KB -> 1 block/CU -> 2 waves/SIMD. amdgpu_waves_per_eu(2,2) pins the
// allocator's occupancy TARGET at 2 (256-VGPR budget): r7 showed
// __launch_bounds__(512,2) only caps regs; the allocator still targeted 4
// waves/EU (128 regs) and spilled ~750MB/dispatch to HBM.
// Structurally reduced live set as hedge: per-t x-frag loads + inline LN
// (no htp[4][4], no xf[4][2]) -> peak live ~120 regs.
// A = weights (M=16 gate-dims/tile x K), B = state (K x N=16 rows); identical
// (lanegroup,slot)->k map on both sides => k-order invariant.
// C/D: col(lane&15)=row, M=4*(lane>>4)+reg [m89-verified].
// ---------------------------------------------------------------------------
__global__ __attribute__((amdgpu_waves_per_eu(2, 2))) __launch_bounds__(512)
void tower_kernel(const float* __restrict__ uEmbed, const float* __restrict__ iEmbed,
                  const float* __restrict__ Wih, const float* __restrict__ Whh,
                  const float* __restrict__ bih, const float* __restrict__ bhh,
                  const float* __restrict__ Wq0, const float* __restrict__ Wk0, const float* __restrict__ Wv0,
                  const float* __restrict__ Wq1, const float* __restrict__ Wk1, const float* __restrict__ Wv1,
                  float* __restrict__ finalv)
{
    __shared__ char WFRAG[65536];   // LSTM: 64 frags (m*4+kc)*1024; later 48 QKV frags
    __shared__ float BSL[256];
    __shared__ char STG[32768];     // per-wave 4KB: [0,2K) h-stage, [2K,4K) xn-stage

    const int tid  = threadIdx.x;
    const int lane = tid & 63;
    const int wave = tid >> 6;
    const int r    = lane & 15;
    const int g    = lane >> 4;

    // ---- stage LSTM weight fragments (bf16) ----
#pragma unroll
    for (int i = 0; i < 8; ++i) {
        int f = wave * 8 + i;               // 0..63
        int m = f >> 2, kc = f & 3;
        int gate = m * 16 + r;
        int k0 = kc * 32 + 8 * g;
        const float* src = (k0 < 64) ? (Wih + gate * 64 + k0)
                                     : (Whh + gate * 64 + (k0 - 64));
        float4 lo = *(const float4*)src;
        float4 hi = *(const float4*)(src + 4);
        U16B u;
        u.u[0] = pkbf(lo.x, lo.y); u.u[1] = pkbf(lo.z, lo.w);
        u.u[2] = pkbf(hi.x, hi.y); u.u[3] = pkbf(hi.z, hi.w);
        *(bf16x8*)(WFRAG + f * 1024 + lane * 16) = u.v;
    }
    if (tid < 256) BSL[tid] = bih[tid] + bhh[tid];
    __syncthreads();

    const int rowBase0 = blockIdx.x * 128 + wave * 16;
    const bool active  = rowBase0 < N_ROWS;            // wave-uniform (16 | N_ROWS)
    const int rowBase  = active ? rowBase0 : (N_ROWS - 16);
    const bool isUser = rowBase < U_CNT;               // 16 | 100000 -> wave-uniform
    const float* emb = isUser ? uEmbed : iEmbed;
    const int cnt = isUser ? U_CNT : I_CNT;
    const int rloc = (isUser ? rowBase : rowBase - U_CNT) + r;

    char* stg_h = STG + wave * 4096;
    char* stg_x = stg_h + 2048;

    float cst[4][4];
#pragma unroll
    for (int mm = 0; mm < 4; ++mm)
#pragma unroll
        for (int rg = 0; rg < 4; ++rg) cst[mm][rg] = 0.0f;

    bf16x8 xnf[4][2];               // LN'd h, B-frag form, built inline per t

#pragma unroll
    for (int t = 0; t < 4; ++t) {
        // ---- x B-frags for this step (x3.0, bf16) ----
        bf16x8 xft[2];
#pragma unroll
        for (int c = 0; c < 2; ++c) {
            const float* p = emb + ((size_t)t * cnt + rloc) * 64 + c * 32 + 8 * g;
            float4 lo = *(const float4*)p;
            float4 hi = *(const float4*)(p + 4);
            U16B u;
            u.u[0] = pkbf(3.0f * lo.x, 3.0f * lo.y);
            u.u[1] = pkbf(3.0f * lo.z, 3.0f * lo.w);
            u.u[2] = pkbf(3.0f * hi.x, 3.0f * hi.y);
            u.u[3] = pkbf(3.0f * hi.z, 3.0f * hi.w);
            xft[c] = u.v;
        }

        f32x4 acc[16];
#pragma unroll
        for (int m = 0; m < 16; ++m)
            acc[m] = *(const f32x4*)((const char*)BSL + m * 64 + g * 16);  // bias bcast
#pragma unroll
        for (int kc = 0; kc < 2; ++kc) {
#pragma unroll
            for (int m = 0; m < 16; ++m) {
                bf16x8 af = *(const bf16x8*)(WFRAG + (m * 4 + kc) * 1024 + lane * 16);
                acc[m] = __builtin_amdgcn_mfma_f32_16x16x32_bf16(af, xft[kc], acc[m], 0, 0, 0);
            }
        }
        if (t > 0) {
#pragma unroll
            for (int c = 0; c < 2; ++c) {
                int p0 = (8 * c + 2 * g) ^ r;
                int p1 = (8 * c + 2 * g + 1) ^ r;
                uint2 ua = *(const uint2*)(stg_h + r * 128 + (p0 << 3));
                uint2 ub = *(const uint2*)(stg_h + r * 128 + (p1 << 3));
                U16B u; u.u[0] = ua.x; u.u[1] = ua.y; u.u[2] = ub.x; u.u[3] = ub.y;
#pragma unroll
                for (int m = 0; m < 16; ++m) {
                    bf16x8 af = *(const bf16x8*)(WFRAG + (m * 4 + 2 + c) * 1024 + lane * 16);
                    acc[m] = __builtin_amdgcn_mfma_f32_16x16x32_bf16(af, u.v, acc[m], 0, 0, 0);
                }
            }
        }

        // ---- elementwise gates; d = mm*16 + 4g + reg, gate m = type*4 + mm ----
        uint2 hp4[4];
#pragma unroll
        for (int mm = 0; mm < 4; ++mm) {
            float hv[4];
#pragma unroll
            for (int rg = 0; rg < 4; ++rg) {
                float iv = acc[mm][rg];
                float fv = acc[4 + mm][rg];
                float gv = acc[8 + mm][rg];
                float ov = acc[12 + mm][rg];
                float cc = sigm(fv) * cst[mm][rg] + sigm(iv) * tanh_(gv);
                cst[mm][rg] = cc;
                hv[rg] = sigm(ov) * tanh_(cc);
            }
            hp4[mm].x = pkbf(hv[0], hv[1]);
            hp4[mm].y = pkbf(hv[2], hv[3]);
            if (t < 3)
                *(uint2*)(stg_h + r * 128 + (((mm * 4 + g) ^ r) << 3)) = hp4[mm];
        }

        // ---- inline LayerNorm over this row's 64 dims (on bf16-rounded h) ----
        {
            float hv[16];
#pragma unroll
            for (int mm = 0; mm < 4; ++mm) {
                hv[mm * 4 + 0] = bf_lo(hp4[mm].x); hv[mm * 4 + 1] = bf_hi(hp4[mm].x);
                hv[mm * 4 + 2] = bf_lo(hp4[mm].y); hv[mm * 4 + 3] = bf_hi(hp4[mm].y);
            }
            float s = 0.f, s2 = 0.f;
#pragma unroll
            for (int i2 = 0; i2 < 16; ++i2) { s += hv[i2]; s2 += hv[i2] * hv[i2]; }
            s  += __shfl_xor(s, 16, 64);  s  += __shfl_xor(s, 32, 64);
            s2 += __shfl_xor(s2, 16, 64); s2 += __shfl_xor(s2, 32, 64);
            float mean = s * (1.f / 64.f);
            float var  = s2 * (1.f / 64.f) - mean * mean;
            float rs = rsqrtf(var + 1e-5f);
#pragma unroll
            for (int mm = 0; mm < 4; ++mm) {
                float x0 = (hv[mm * 4 + 0] - mean) * rs, x1 = (hv[mm * 4 + 1] - mean) * rs;
                float x2 = (hv[mm * 4 + 2] - mean) * rs, x3 = (hv[mm * 4 + 3] - mean) * rs;
                uint2 xp; xp.x = pkbf(x0, x1); xp.y = pkbf(x2, x3);
                *(uint2*)(stg_x + r * 128 + (((mm * 4 + g) ^ r) << 3)) = xp;
            }
#pragma unroll
            for (int c = 0; c < 2; ++c) {
                int p0 = (8 * c + 2 * g) ^ r, p1 = (8 * c + 2 * g + 1) ^ r;
                uint2 ua = *(const uint2*)(stg_x + r * 128 + (p0 << 3));
                uint2 ub = *(const uint2*)(stg_x + r * 128 + (p1 << 3));
                U16B u; u.u[0] = ua.x; u.u[1] = ua.y; u.u[2] = ub.x; u.u[3] = ub.y;
                xnf[t][c] = u.v;
            }
        }
    }

    // ---- restage W region with 6 QKV matrices as A-frags ----
    __syncthreads();
#pragma unroll
    for (int i = 0; i < 6; ++i) {
        int f = 8 * i + wave;                   // mat6 = i, slot = wave = m*2+kc
        int m = (wave >> 1) & 3, kc = wave & 1;
        const float* WM = (i == 0) ? Wq0 : (i == 1) ? Wk0 : (i == 2) ? Wv0
                        : (i == 3) ? Wq1 : (i == 4) ? Wk1 : Wv1;
        int dp = m * 16 + r;
        int k0 = kc * 32 + 8 * g;
        float v0 = WM[(k0 + 0) * 64 + dp], v1 = WM[(k0 + 1) * 64 + dp];
        float v2 = WM[(k0 + 2) * 64 + dp], v3 = WM[(k0 + 3) * 64 + dp];
        float v4 = WM[(k0 + 4) * 64 + dp], v5 = WM[(k0 + 5) * 64 + dp];
        float v6 = WM[(k0 + 6) * 64 + dp], v7 = WM[(k0 + 7) * 64 + dp];
        U16B u;
        u.u[0] = pkbf(v0, v1); u.u[1] = pkbf(v2, v3);
        u.u[2] = pkbf(v4, v5); u.u[3] = pkbf(v6, v7);
        *(bf16x8*)(WFRAG + f * 1024 + lane * 16) = u.v;
    }
    __syncthreads();

    const int base3 = isUser ? 0 : 3;

    // ---- K and V via MFMA first (packed bf16: 32+32 regs) ----
    uint2 kpk[4][4], vpk[4][4];
#pragma unroll
    for (int t = 0; t < 4; ++t) {
#pragma unroll
        for (int m = 0; m < 4; ++m) {
            f32x4 ak = {0.f, 0.f, 0.f, 0.f};
            f32x4 av = {0.f, 0.f, 0.f, 0.f};
#pragma unroll
            for (int kc = 0; kc < 2; ++kc) {
                bf16x8 afk = *(const bf16x8*)(WFRAG + ((1 + base3) * 8 + m * 2 + kc) * 1024 + lane * 16);
                bf16x8 afv = *(const bf16x8*)(WFRAG + ((2 + base3) * 8 + m * 2 + kc) * 1024 + lane * 16);
                ak = __builtin_amdgcn_mfma_f32_16x16x32_bf16(afk, xnf[t][kc], ak, 0, 0, 0);
                av = __builtin_amdgcn_mfma_f32_16x16x32_bf16(afv, xnf[t][kc], av, 0, 0, 0);
            }
            uint2 pk; pk.x = pkbf(ak[0], ak[1]); pk.y = pkbf(ak[2], ak[3]);
            kpk[t][m] = pk;
            uint2 pv; pv.x = pkbf(av[0], av[1]); pv.y = pkbf(av[2], av[3]);
            vpk[t][m] = pv;
        }
    }

    // ---- per-t: Q (f32, never packed) + attention; head = m tile ----
    float outv[4][4];
#pragma unroll
    for (int mm = 0; mm < 4; ++mm)
#pragma unroll
        for (int rg = 0; rg < 4; ++rg) outv[mm][rg] = 0.f;

#pragma unroll
    for (int t = 0; t < 4; ++t) {
        float qv[4][4];
#pragma unroll
        for (int m = 0; m < 4; ++m) {
            f32x4 aq = {0.f, 0.f, 0.f, 0.f};
#pragma unroll
            for (int kc = 0; kc < 2; ++kc) {
                bf16x8 afq = *(const bf16x8*)(WFRAG + ((0 + base3) * 8 + m * 2 + kc) * 1024 + lane * 16);
                aq = __builtin_amdgcn_mfma_f32_16x16x32_bf16(afq, xnf[t][kc], aq, 0, 0, 0);
            }
            qv[m][0] = aq[0]; qv[m][1] = aq[1]; qv[m][2] = aq[2]; qv[m][3] = aq[3];
        }
        float sc[4][4];                 // [s][mm]
#pragma unroll
        for (int s5 = 0; s5 < 4; ++s5) {
#pragma unroll
            for (int mm = 0; mm < 4; ++mm) {
                uint2 p = kpk[s5][mm];
                float pr = qv[mm][0] * bf_lo(p.x) + qv[mm][1] * bf_hi(p.x)
                         + qv[mm][2] * bf_lo(p.y) + qv[mm][3] * bf_hi(p.y);
                pr += __shfl_xor(pr, 16, 64);
                pr += __shfl_xor(pr, 32, 64);
                sc[s5][mm] = pr * 0.25f;
            }
        }
#pragma unroll
        for (int mm = 0; mm < 4; ++mm) {
            float mx = fmaxf(fmaxf(sc[0][mm], sc[1][mm]), fmaxf(sc[2][mm], sc[3][mm]));
            float e0 = __expf(sc[0][mm] - mx), e1 = __expf(sc[1][mm] - mx);
            float e2 = __expf(sc[2][mm] - mx), e3 = __expf(sc[3][mm] - mx);
            float inv = 1.f / (e0 + e1 + e2 + e3);
            float a0 = e0 * inv, a1 = e1 * inv, a2 = e2 * inv, a3 = e3 * inv;
            uint2 p0 = vpk[0][mm], p1 = vpk[1][mm], p2 = vpk[2][mm], p3 = vpk[3][mm];
            outv[mm][0] += a0 * bf_lo(p0.x) + a1 * bf_lo(p1.x) + a2 * bf_lo(p2.x) + a3 * bf_lo(p3.x);
            outv[mm][1] += a0 * bf_hi(p0.x) + a1 * bf_hi(p1.x) + a2 * bf_hi(p2.x) + a3 * bf_hi(p3.x);
            outv[mm][2] += a0 * bf_lo(p0.y) + a1 * bf_lo(p1.y) + a2 * bf_lo(p2.y) + a3 * bf_lo(p3.y);
            outv[mm][3] += a0 * bf_hi(p0.y) + a1 * bf_hi(p1.y) + a2 * bf_hi(p2.y) + a3 * bf_hi(p3.y);
        }
    }

    if (active) {
        float* dst = finalv + (size_t)(rowBase + r) * 64;
#pragma unroll
        for (int mm = 0; mm < 4; ++mm) {
            float4 o4 = { outv[mm][0] * 0.25f, outv[mm][1] * 0.25f,
                          outv[mm][2] * 0.25f, outv[mm][3] * 0.25f };
            *(float4*)(dst + mm * 16 + 4 * g) = o4;
        }
    }
}

// ---------------------------------------------------------------------------
// Sequence aggregation + 2 degenerate (T=1) attention layers -> att_user (B,64)
// ---------------------------------------------------------------------------
__global__ __launch_bounds__(256)
void seq_att_kernel(const float* __restrict__ finalv, const float* __restrict__ posEmbed,
                    const float* __restrict__ mask, const int* __restrict__ sequence,
                    const float* __restrict__ Wv_seq, float* __restrict__ att_user)
{
    const int lane = threadIdx.x & 63, wave = threadIdx.x >> 6;
    const int b = blockIdx.x * 4 + wave;
    if (b >= B_CNT) return;
    const float* fitem = finalv + (size_t)U_CNT * D_DIM;

    float acc = 0.0f;
    for (int l = 0; l < L_SEQ; ++l) {
        int   sid = sequence[b * L_SEQ + l];
        float m   = mask[b * L_SEQ + l];
        acc += m * (fitem[(size_t)sid * D_DIM + lane] + posEmbed[l * D_DIM + lane]);
    }
    float att = waveLayerNorm(acc);   // sb
#pragma unroll
    for (int layer = 0; layer < 2; ++layer) {
        float xnv = waveLayerNorm(att);
        float vv = 0.0f;
        const float* Wv = Wv_seq + layer * 64 * 64;
        for (int j = 0; j < 64; ++j)
            vv = fmaf(bcast(xnv, j), Wv[j * 64 + lane], vv);
        att = leakyf(vv) + att;
    }
    att_user[b * D_DIM + lane] = att;
}

// ---------------------------------------------------------------------------
// preds[n] = <fu[uids], fi[iids]> + <leaky(att_user[uLocs]), fi[iids]>
// ---------------------------------------------------------------------------
__global__ __launch_bounds__(256)
void preds_kernel(const float* __restrict__ finalv, const float* __restrict__ att_user,
                  const int* __restrict__ uids, const int* __restrict__ iids,
                  const int* __restrict__ uLocs, float* __restrict__ out)
{
    const int lane = threadIdx.x & 63, wave = threadIdx.x >> 6;
    const int n = blockIdx.x * 4 + wave;
    if (n >= NPRED) return;
    const int u = uids[n], it = iids[n], loc = uLocs[n];
    float fi = finalv[(size_t)(U_CNT + it) * D_DIM + lane];
    float fu = finalv[(size_t)u * D_DIM + lane];
    float au = leakyf(att_user[loc * D_DIM + lane]);
    float p = waveReduceSum(fu * fi + au * fi);
    if (lane == 0) out[n] = p;
}

// ---------------------------------------------------------------------------
// Per (g,s) sample: user_weight (meta MLP), S_final, p1
// ---------------------------------------------------------------------------
__global__ __launch_bounds__(256)
void pergs_kernel(const float* __restrict__ finalv,
                  const float* __restrict__ uEmbed, const float* __restrict__ iEmbed,
                  const int* __restrict__ suids, const int* __restrict__ siids,
                  const float* __restrict__ W2, const float* __restrict__ b2,
                  const float* __restrict__ W3, const float* __restrict__ b3,
                  float* __restrict__ uw, float* __restrict__ SfB, float* __restrict__ p1B)
{
    const int lane = threadIdx.x & 63, wave = threadIdx.x >> 6;
    const int idx = blockIdx.x * 4 + wave;        // 0 .. G*NS-1
    if (idx >= G_CNT * NS_CNT) return;
    const int g  = idx >> 12;                     // NS_CNT == 4096
    const int su = suids[idx], si = siids[idx];

    float fu = finalv[(size_t)su * D_DIM + lane];
    float fi = finalv[(size_t)(U_CNT + si) * D_DIM + lane];
    float uv = 3.0f * uEmbed[((size_t)g * U_CNT + su) * D_DIM + lane];
    float iv = 3.0f * iEmbed[((size_t)g * I_CNT + si) * D_DIM + lane];

    float sf = waveReduceSum(leakyf(fu * fi));
    float pp = waveReduceSum(leakyf(uv * iv));

    float m1a = fu * uv;
    float acc3 = 0.0f;
    for (int o = 0; o < 32; ++o) {
        float part = m1a * W2[o * 192 + lane]
                   + fu  * W2[o * 192 + 64 + lane]
                   + uv  * W2[o * 192 + 128 + lane];
        part = waveReduceSum(part);
        float m2 = leakyf(part + b2[o]);
        acc3 = fmaf(m2, W3[o], acc3);
    }
    float w = sigm(acc3 + b3[0]);
    if (lane == 0) { uw[idx] = w; SfB[idx] = sf; p1B[idx] = pp; }
}

// ---------------------------------------------------------------------------
// Final hinge loss, single block (deterministic)
// ---------------------------------------------------------------------------
__global__ __launch_bounds__(1024)
void ssl_kernel(const float* __restrict__ uw, const float* __restrict__ SfB,
                const float* __restrict__ p1B, float* __restrict__ out)
{
    const int tid = threadIdx.x;
    float local = 0.0f;
    for (int p = tid; p < G_CNT * 2048; p += 1024) {
        int g = p >> 11, s = p & 2047;
        int ip = g * NS_CNT + s, in_ = ip + 2048;
        float Sf   = uw[ip] * SfB[ip] - uw[in_] * SfB[in_];
        float diff = p1B[ip] - p1B[in_];
        local += fmaxf(1.0f - Sf * diff, 0.0f);
    }
    local = waveReduceSum(local);
    __shared__ float part[16];
    const int wave = tid >> 6, lane = tid & 63;
    if (lane == 0) part[wave] = local;
    __syncthreads();
    if (tid == 0) {
        float s = 0.0f;
        for (int i = 0; i < 16; ++i) s += part[i];
        out[NPRED] = s;
    }
}

extern "C" void kernel_launch(void* const* d_in, const int* in_sizes, int n_in,
                              void* d_out, int out_size, void* d_ws, size_t ws_size,
                              hipStream_t stream)
{
    const float* uEmbed  = (const float*)d_in[0];
    const float* iEmbed  = (const float*)d_in[1];
    const float* posEmbed= (const float*)d_in[2];
    const float* Wih     = (const float*)d_in[3];
    const float* Whh     = (const float*)d_in[4];
    const float* bih     = (const float*)d_in[5];
    const float* bhh     = (const float*)d_in[6];
    const float* Wq0     = (const float*)d_in[7];
    const float* Wk0     = (const float*)d_in[8];
    const float* Wv0     = (const float*)d_in[9];
    const float* Wq1     = (const float*)d_in[10];
    const float* Wk1     = (const float*)d_in[11];
    const float* Wv1     = (const float*)d_in[12];
    const float* Wv_seq  = (const float*)d_in[15];
    const float* meta2_W = (const float*)d_in[16];
    const float* meta2_b = (const float*)d_in[17];
    const float* meta3_W = (const float*)d_in[18];
    const float* meta3_b = (const float*)d_in[19];
    const float* mask    = (const float*)d_in[20];
    const int*   uids    = (const int*)d_in[21];
    const int*   iids    = (const int*)d_in[22];
    const int*   sequence= (const int*)d_in[23];
    const int*   uLocs   = (const int*)d_in[24];
    const int*   suids   = (const int*)d_in[25];
    const int*   siids   = (const int*)d_in[26];

    float* finalv   = (float*)d_ws;                       // N_ROWS*64
    float* att_user = finalv + (size_t)N_ROWS * D_DIM;    // B*64
    float* uwB      = att_user + (size_t)B_CNT * D_DIM;   // G*NS
    float* SfB      = uwB + (size_t)G_CNT * NS_CNT;
    float* p1B      = SfB + (size_t)G_CNT * NS_CNT;
    float* out      = (float*)d_out;

    tower_kernel<<<(N_ROWS + 127) / 128, 512, 0, stream>>>(
        uEmbed, iEmbed, Wih, Whh, bih, bhh, Wq0, Wk0, Wv0, Wq1, Wk1, Wv1, finalv);

    seq_att_kernel<<<(B_CNT + 3) / 4, 256, 0, stream>>>(
        finalv, posEmbed, mask, sequence, Wv_seq, att_user);

    pergs_kernel<<<(G_CNT * NS_CNT) / 4, 256, 0, stream>>>(
        finalv, uEmbed, iEmbed, suids, siids, meta2_W, meta2_b, meta3_W, meta3_b,
        uwB, SfB, p1B);

    preds_kernel<<<NPRED / 4, 256, 0, stream>>>(finalv, att_user, uids, iids, uLocs, out);

    ssl_kernel<<<1, 1024, 0, stream>>>(uwB, SfB, p1B, out);
}

// Round 9
// 286.967 us; speedup vs baseline: 5.6600x; 1.3713x over previous
//
#include <hip/hip_runtime.h>
#include <hip/hip_bf16.h>
#include <math.h>

#define G_CNT 4
#define U_CNT 100000
#define I_CNT 50000
#define N_ROWS (U_CNT + I_CNT)
#define D_DIM 64
#define T_STEPS 4
#define L_SEQ 50
#define B_CNT 2048
#define NPRED 8192
#define NS_CNT 4096
#define LEAKY_A 0.5f

typedef short bf16x8 __attribute__((ext_vector_type(8)));
typedef float f32x4 __attribute__((ext_vector_type(4)));

union U16B { unsigned u[4]; bf16x8 v; };

// f32 -> bf16 RNE, pure C (no inline asm)
__device__ __forceinline__ unsigned bfr(float x) {
    unsigned u = __float_as_uint(x);
    return (u + 0x7fffu + ((u >> 16) & 1u)) >> 16;
}
__device__ __forceinline__ unsigned pkbf(float a, float b) {
    return bfr(a) | (bfr(b) << 16);
}
__device__ __forceinline__ float bf_lo(unsigned u) { return __uint_as_float(u << 16); }
__device__ __forceinline__ float bf_hi(unsigned u) { return __uint_as_float(u & 0xffff0000u); }

__device__ __forceinline__ float bcast(float v, int srcLane) {
    return __int_as_float(__builtin_amdgcn_readlane(__float_as_int(v), srcLane));
}

__device__ __forceinline__ float waveReduceSum(float v) {
    v += __shfl_xor(v, 1, 64);
    v += __shfl_xor(v, 2, 64);
    v += __shfl_xor(v, 4, 64);
    v += __shfl_xor(v, 8, 64);
    v += __shfl_xor(v, 16, 64);
    v += __shfl_xor(v, 32, 64);
    return v;
}

__device__ __forceinline__ float waveLayerNorm(float v) {
    float s  = waveReduceSum(v);
    float s2 = waveReduceSum(v * v);
    float mean = s * (1.0f / 64.0f);
    float var  = s2 * (1.0f / 64.0f) - mean * mean;
    return (v - mean) * rsqrtf(var + 1e-5f);
}

__device__ __forceinline__ float sigm(float x) { return 1.0f / (1.0f + __expf(-x)); }
__device__ __forceinline__ float tanh_(float x) {
    float xc = fminf(x, 15.0f);
    float t = __expf(2.0f * xc);
    return (t - 1.0f) / (t + 1.0f);
}
__device__ __forceinline__ float leakyf(float x) { return x >= 0.0f ? x : LEAKY_A * x; }

// ---------------------------------------------------------------------------
// prep_kernel: one-shot pack of weight fragments into d_ws (L2-resident table).
//   frag f (0..63):  LSTM, f = m*4+kc, lane gives (r,g); bytes f*1024 + lane*16
//   frag 64+i*8+s:   QKV mat i (q0,k0,v0,q1,k1,v1), slot s = m*2+kc
//   biastab: 256 floats (bih+bhh)
// ---------------------------------------------------------------------------
__global__ __launch_bounds__(512)
void prep_kernel(const float* __restrict__ Wih, const float* __restrict__ Whh,
                 const float* __restrict__ bih, const float* __restrict__ bhh,
                 const float* __restrict__ Wq0, const float* __restrict__ Wk0, const float* __restrict__ Wv0,
                 const float* __restrict__ Wq1, const float* __restrict__ Wk1, const float* __restrict__ Wv1,
                 char* __restrict__ fragtab, float* __restrict__ biastab)
{
    const int tid  = threadIdx.x;
    const int lane = tid & 63;
    const int wave = tid >> 6;
    const int r    = lane & 15;
    const int g    = lane >> 4;

#pragma unroll
    for (int i = 0; i < 8; ++i) {
        int f = wave * 8 + i;               // 0..63
        int m = f >> 2, kc = f & 3;
        int gate = m * 16 + r;
        int k0 = kc * 32 + 8 * g;
        const float* src = (k0 < 64) ? (Wih + gate * 64 + k0)
                                     : (Whh + gate * 64 + (k0 - 64));
        float4 lo = *(const float4*)src;
        float4 hi = *(const float4*)(src + 4);
        U16B u;
        u.u[0] = pkbf(lo.x, lo.y); u.u[1] = pkbf(lo.z, lo.w);
        u.u[2] = pkbf(hi.x, hi.y); u.u[3] = pkbf(hi.z, hi.w);
        *(bf16x8*)(fragtab + f * 1024 + lane * 16) = u.v;
    }
#pragma unroll
    for (int i = 0; i < 6; ++i) {
        int f = 64 + i * 8 + wave;              // slot = wave = m*2+kc
        int m = (wave >> 1) & 3, kc = wave & 1;
        const float* WM = (i == 0) ? Wq0 : (i == 1) ? Wk0 : (i == 2) ? Wv0
                        : (i == 3) ? Wq1 : (i == 4) ? Wk1 : Wv1;
        int dp = m * 16 + r;
        int k0 = kc * 32 + 8 * g;
        float v0 = WM[(k0 + 0) * 64 + dp], v1 = WM[(k0 + 1) * 64 + dp];
        float v2 = WM[(k0 + 2) * 64 + dp], v3 = WM[(k0 + 3) * 64 + dp];
        float v4 = WM[(k0 + 4) * 64 + dp], v5 = WM[(k0 + 5) * 64 + dp];
        float v6 = WM[(k0 + 6) * 64 + dp], v7 = WM[(k0 + 7) * 64 + dp];
        U16B u;
        u.u[0] = pkbf(v0, v1); u.u[1] = pkbf(v2, v3);
        u.u[2] = pkbf(v4, v5); u.u[3] = pkbf(v6, v7);
        *(bf16x8*)(fragtab + f * 1024 + lane * 16) = u.v;
    }
    if (tid < 256) biastab[tid] = bih[tid] + bhh[tid];
}

// ---------------------------------------------------------------------------
// MFMA tower: 8 waves/block, 16 rows/wave; grid = ceil(N_ROWS/128) = 1172.
// A-frags from global fragtab (112KB, L2-hot) -> no WFRAG LDS, no barriers;
// LDS = 32KB h/xn stage only -> 2 blocks/CU = 4 waves/SIMD.
// Attention per-head (q,k,v f32, 48 transient regs) -> peak live ~105 regs,
// fits the 128-VGPR budget with zero spill (r7: 178MB/dispatch spill writes).
// A = weights (M=16 gate-dims/tile x K), B = state (K x N=16 rows); identical
// (lanegroup,slot)->k map on both sides => k-order invariant.
// C/D: col(lane&15)=row, M=4*(lane>>4)+reg [m89-verified].
// ---------------------------------------------------------------------------
__global__ __launch_bounds__(512)
void tower_kernel(const float* __restrict__ uEmbed, const float* __restrict__ iEmbed,
                  const char* __restrict__ fragtab, const float* __restrict__ biastab,
                  float* __restrict__ finalv)
{
    __shared__ char STG[32768];     // per-wave 4KB: [0,2K) h-stage, [2K,4K) xn-stage

    const int tid  = threadIdx.x;
    const int lane = tid & 63;
    const int wave = tid >> 6;
    const int r    = lane & 15;
    const int g    = lane >> 4;

    const int rowBase0 = blockIdx.x * 128 + wave * 16;
    const bool active  = rowBase0 < N_ROWS;            // wave-uniform (16 | N_ROWS)
    const int rowBase  = active ? rowBase0 : (N_ROWS - 16);
    const bool isUser = rowBase < U_CNT;               // 16 | 100000 -> wave-uniform
    const float* emb = isUser ? uEmbed : iEmbed;
    const int cnt = isUser ? U_CNT : I_CNT;
    const int rloc = (isUser ? rowBase : rowBase - U_CNT) + r;

    char* stg_h = STG + wave * 4096;
    char* stg_x = stg_h + 2048;

    float cst[4][4];
#pragma unroll
    for (int mm = 0; mm < 4; ++mm)
#pragma unroll
        for (int rg = 0; rg < 4; ++rg) cst[mm][rg] = 0.0f;

    bf16x8 xnf[4][2];               // LN'd h, B-frag form, built inline per t

#pragma unroll
    for (int t = 0; t < 4; ++t) {
        // ---- x B-frags for this step (x3.0, bf16) ----
        bf16x8 xft[2];
#pragma unroll
        for (int c = 0; c < 2; ++c) {
            const float* p = emb + ((size_t)t * cnt + rloc) * 64 + c * 32 + 8 * g;
            float4 lo = *(const float4*)p;
            float4 hi = *(const float4*)(p + 4);
            U16B u;
            u.u[0] = pkbf(3.0f * lo.x, 3.0f * lo.y);
            u.u[1] = pkbf(3.0f * lo.z, 3.0f * lo.w);
            u.u[2] = pkbf(3.0f * hi.x, 3.0f * hi.y);
            u.u[3] = pkbf(3.0f * hi.z, 3.0f * hi.w);
            xft[c] = u.v;
        }

        f32x4 acc[16];
#pragma unroll
        for (int m = 0; m < 16; ++m)
            acc[m] = *(const f32x4*)((const char*)biastab + m * 64 + g * 16);  // bias bcast
#pragma unroll
        for (int kc = 0; kc < 2; ++kc) {
#pragma unroll
            for (int m = 0; m < 16; ++m) {
                bf16x8 af = *(const bf16x8*)(fragtab + (m * 4 + kc) * 1024 + lane * 16);
                acc[m] = __builtin_amdgcn_mfma_f32_16x16x32_bf16(af, xft[kc], acc[m], 0, 0, 0);
            }
        }
        if (t > 0) {
#pragma unroll
            for (int c = 0; c < 2; ++c) {
                int p0 = (8 * c + 2 * g) ^ r;
                int p1 = (8 * c + 2 * g + 1) ^ r;
                uint2 ua = *(const uint2*)(stg_h + r * 128 + (p0 << 3));
                uint2 ub = *(const uint2*)(stg_h + r * 128 + (p1 << 3));
                U16B u; u.u[0] = ua.x; u.u[1] = ua.y; u.u[2] = ub.x; u.u[3] = ub.y;
#pragma unroll
                for (int m = 0; m < 16; ++m) {
                    bf16x8 af = *(const bf16x8*)(fragtab + (m * 4 + 2 + c) * 1024 + lane * 16);
                    acc[m] = __builtin_amdgcn_mfma_f32_16x16x32_bf16(af, u.v, acc[m], 0, 0, 0);
                }
            }
        }

        // ---- elementwise gates; d = mm*16 + 4g + reg, gate m = type*4 + mm ----
        uint2 hp4[4];
#pragma unroll
        for (int mm = 0; mm < 4; ++mm) {
            float hv[4];
#pragma unroll
            for (int rg = 0; rg < 4; ++rg) {
                float iv = acc[mm][rg];
                float fv = acc[4 + mm][rg];
                float gv = acc[8 + mm][rg];
                float ov = acc[12 + mm][rg];
                float cc = sigm(fv) * cst[mm][rg] + sigm(iv) * tanh_(gv);
                cst[mm][rg] = cc;
                hv[rg] = sigm(ov) * tanh_(cc);
            }
            hp4[mm].x = pkbf(hv[0], hv[1]);
            hp4[mm].y = pkbf(hv[2], hv[3]);
            if (t < 3)
                *(uint2*)(stg_h + r * 128 + (((mm * 4 + g) ^ r) << 3)) = hp4[mm];
        }

        // ---- inline LayerNorm over this row's 64 dims (on bf16-rounded h) ----
        {
            float hv[16];
#pragma unroll
            for (int mm = 0; mm < 4; ++mm) {
                hv[mm * 4 + 0] = bf_lo(hp4[mm].x); hv[mm * 4 + 1] = bf_hi(hp4[mm].x);
                hv[mm * 4 + 2] = bf_lo(hp4[mm].y); hv[mm * 4 + 3] = bf_hi(hp4[mm].y);
            }
            float s = 0.f, s2 = 0.f;
#pragma unroll
            for (int i2 = 0; i2 < 16; ++i2) { s += hv[i2]; s2 += hv[i2] * hv[i2]; }
            s  += __shfl_xor(s, 16, 64);  s  += __shfl_xor(s, 32, 64);
            s2 += __shfl_xor(s2, 16, 64); s2 += __shfl_xor(s2, 32, 64);
            float mean = s * (1.f / 64.f);
            float var  = s2 * (1.f / 64.f) - mean * mean;
            float rs = rsqrtf(var + 1e-5f);
#pragma unroll
            for (int mm = 0; mm < 4; ++mm) {
                float x0 = (hv[mm * 4 + 0] - mean) * rs, x1 = (hv[mm * 4 + 1] - mean) * rs;
                float x2 = (hv[mm * 4 + 2] - mean) * rs, x3 = (hv[mm * 4 + 3] - mean) * rs;
                uint2 xp; xp.x = pkbf(x0, x1); xp.y = pkbf(x2, x3);
                *(uint2*)(stg_x + r * 128 + (((mm * 4 + g) ^ r) << 3)) = xp;
            }
#pragma unroll
            for (int c = 0; c < 2; ++c) {
                int p0 = (8 * c + 2 * g) ^ r, p1 = (8 * c + 2 * g + 1) ^ r;
                uint2 ua = *(const uint2*)(stg_x + r * 128 + (p0 << 3));
                uint2 ub = *(const uint2*)(stg_x + r * 128 + (p1 << 3));
                U16B u; u.u[0] = ua.x; u.u[1] = ua.y; u.u[2] = ub.x; u.u[3] = ub.y;
                xnf[t][c] = u.v;
            }
        }
    }

    // ---- per-head QKV (f32, no packing) + attention; head = m tile ----
    const int base3 = isUser ? 0 : 3;
    float* dst = finalv + (size_t)(rowBase + r) * 64;

#pragma unroll
    for (int mm = 0; mm < 4; ++mm) {
        float q[4][4], k[4][4], v[4][4];
#pragma unroll
        for (int t = 0; t < 4; ++t) {
            f32x4 aq = {0.f, 0.f, 0.f, 0.f};
            f32x4 ak = {0.f, 0.f, 0.f, 0.f};
            f32x4 av = {0.f, 0.f, 0.f, 0.f};
#pragma unroll
            for (int kc = 0; kc < 2; ++kc) {
                const bf16x8 bq = *(const bf16x8*)(fragtab + (size_t)(64 + (0 + base3) * 8 + mm * 2 + kc) * 1024 + lane * 16);
                const bf16x8 bk = *(const bf16x8*)(fragtab + (size_t)(64 + (1 + base3) * 8 + mm * 2 + kc) * 1024 + lane * 16);
                const bf16x8 bv = *(const bf16x8*)(fragtab + (size_t)(64 + (2 + base3) * 8 + mm * 2 + kc) * 1024 + lane * 16);
                aq = __builtin_amdgcn_mfma_f32_16x16x32_bf16(bq, xnf[t][kc], aq, 0, 0, 0);
                ak = __builtin_amdgcn_mfma_f32_16x16x32_bf16(bk, xnf[t][kc], ak, 0, 0, 0);
                av = __builtin_amdgcn_mfma_f32_16x16x32_bf16(bv, xnf[t][kc], av, 0, 0, 0);
            }
#pragma unroll
            for (int rg = 0; rg < 4; ++rg) {
                q[t][rg] = aq[rg]; k[t][rg] = ak[rg]; v[t][rg] = av[rg];
            }
        }
        float sc[4][4];                 // [t][s]
#pragma unroll
        for (int t = 0; t < 4; ++t)
#pragma unroll
            for (int s5 = 0; s5 < 4; ++s5) {
                float pr = q[t][0] * k[s5][0] + q[t][1] * k[s5][1]
                         + q[t][2] * k[s5][2] + q[t][3] * k[s5][3];
                pr += __shfl_xor(pr, 16, 64);
                pr += __shfl_xor(pr, 32, 64);
                sc[t][s5] = pr * 0.25f;
            }
        float o0 = 0.f, o1 = 0.f, o2 = 0.f, o3 = 0.f;
#pragma unroll
        for (int t = 0; t < 4; ++t) {
            float mx = fmaxf(fmaxf(sc[t][0], sc[t][1]), fmaxf(sc[t][2], sc[t][3]));
            float e0 = __expf(sc[t][0] - mx), e1 = __expf(sc[t][1] - mx);
            float e2 = __expf(sc[t][2] - mx), e3 = __expf(sc[t][3] - mx);
            float inv = 1.f / (e0 + e1 + e2 + e3);
            float a0 = e0 * inv, a1 = e1 * inv, a2 = e2 * inv, a3 = e3 * inv;
            o0 += a0 * v[0][0] + a1 * v[1][0] + a2 * v[2][0] + a3 * v[3][0];
            o1 += a0 * v[0][1] + a1 * v[1][1] + a2 * v[2][1] + a3 * v[3][1];
            o2 += a0 * v[0][2] + a1 * v[1][2] + a2 * v[2][2] + a3 * v[3][2];
            o3 += a0 * v[0][3] + a1 * v[1][3] + a2 * v[2][3] + a3 * v[3][3];
        }
        if (active) {
            float4 o4 = { o0 * 0.25f, o1 * 0.25f, o2 * 0.25f, o3 * 0.25f };
            *(float4*)(dst + mm * 16 + 4 * g) = o4;
        }
    }
}

// ---------------------------------------------------------------------------
// Sequence aggregation + 2 degenerate (T=1) attention layers -> att_user (B,64)
// ---------------------------------------------------------------------------
__global__ __launch_bounds__(256)
void seq_att_kernel(const float* __restrict__ finalv, const float* __restrict__ posEmbed,
                    const float* __restrict__ mask, const int* __restrict__ sequence,
                    const float* __restrict__ Wv_seq, float* __restrict__ att_user)
{
    const int lane = threadIdx.x & 63, wave = threadIdx.x >> 6;
    const int b = blockIdx.x * 4 + wave;
    if (b >= B_CNT) return;
    const float* fitem = finalv + (size_t)U_CNT * D_DIM;

    float acc = 0.0f;
    for (int l = 0; l < L_SEQ; ++l) {
        int   sid = sequence[b * L_SEQ + l];
        float m   = mask[b * L_SEQ + l];
        acc += m * (fitem[(size_t)sid * D_DIM + lane] + posEmbed[l * D_DIM + lane]);
    }
    float att = waveLayerNorm(acc);   // sb
#pragma unroll
    for (int layer = 0; layer < 2; ++layer) {
        float xnv = waveLayerNorm(att);
        float vv = 0.0f;
        const float* Wv = Wv_seq + layer * 64 * 64;
        for (int j = 0; j < 64; ++j)
            vv = fmaf(bcast(xnv, j), Wv[j * 64 + lane], vv);
        att = leakyf(vv) + att;
    }
    att_user[b * D_DIM + lane] = att;
}

// ---------------------------------------------------------------------------
// preds[n] = <fu[uids], fi[iids]> + <leaky(att_user[uLocs]), fi[iids]>
// ---------------------------------------------------------------------------
__global__ __launch_bounds__(256)
void preds_kernel(const float* __restrict__ finalv, const float* __restrict__ att_user,
                  const int* __restrict__ uids, const int* __restrict__ iids,
                  const int* __restrict__ uLocs, float* __restrict__ out)
{
    const int lane = threadIdx.x & 63, wave = threadIdx.x >> 6;
    const int n = blockIdx.x * 4 + wave;
    if (n >= NPRED) return;
    const int u = uids[n], it = iids[n], loc = uLocs[n];
    float fi = finalv[(size_t)(U_CNT + it) * D_DIM + lane];
    float fu = finalv[(size_t)u * D_DIM + lane];
    float au = leakyf(att_user[loc * D_DIM + lane]);
    float p = waveReduceSum(fu * fi + au * fi);
    if (lane == 0) out[n] = p;
}

// ---------------------------------------------------------------------------
// Per (g,s) sample: user_weight (meta MLP), S_final, p1
// ---------------------------------------------------------------------------
__global__ __launch_bounds__(256)
void pergs_kernel(const float* __restrict__ finalv,
                  const float* __restrict__ uEmbed, const float* __restrict__ iEmbed,
                  const int* __restrict__ suids, const int* __restrict__ siids,
                  const float* __restrict__ W2, const float* __restrict__ b2,
                  const float* __restrict__ W3, const float* __restrict__ b3,
                  float* __restrict__ uw, float* __restrict__ SfB, float* __restrict__ p1B)
{
    const int lane = threadIdx.x & 63, wave = threadIdx.x >> 6;
    const int idx = blockIdx.x * 4 + wave;        // 0 .. G*NS-1
    if (idx >= G_CNT * NS_CNT) return;
    const int g  = idx >> 12;                     // NS_CNT == 4096
    const int su = suids[idx], si = siids[idx];

    float fu = finalv[(size_t)su * D_DIM + lane];
    float fi = finalv[(size_t)(U_CNT + si) * D_DIM + lane];
    float uv = 3.0f * uEmbed[((size_t)g * U_CNT + su) * D_DIM + lane];
    float iv = 3.0f * iEmbed[((size_t)g * I_CNT + si) * D_DIM + lane];

    float sf = waveReduceSum(leakyf(fu * fi));
    float pp = waveReduceSum(leakyf(uv * iv));

    float m1a = fu * uv;
    float acc3 = 0.0f;
    for (int o = 0; o < 32; ++o) {
        float part = m1a * W2[o * 192 + lane]
                   + fu  * W2[o * 192 + 64 + lane]
                   + uv  * W2[o * 192 + 128 + lane];
        part = waveReduceSum(part);
        float m2 = leakyf(part + b2[o]);
        acc3 = fmaf(m2, W3[o], acc3);
    }
    float w = sigm(acc3 + b3[0]);
    if (lane == 0) { uw[idx] = w; SfB[idx] = sf; p1B[idx] = pp; }
}

// ---------------------------------------------------------------------------
// Final hinge loss, single block (deterministic)
// ---------------------------------------------------------------------------
__global__ __launch_bounds__(1024)
void ssl_kernel(const float* __restrict__ uw, const float* __restrict__ SfB,
                const float* __restrict__ p1B, float* __restrict__ out)
{
    const int tid = threadIdx.x;
    float local = 0.0f;
    for (int p = tid; p < G_CNT * 2048; p += 1024) {
        int g = p >> 11, s = p & 2047;
        int ip = g * NS_CNT + s, in_ = ip + 2048;
        float Sf   = uw[ip] * SfB[ip] - uw[in_] * SfB[in_];
        float diff = p1B[ip] - p1B[in_];
        local += fmaxf(1.0f - Sf * diff, 0.0f);
    }
    local = waveReduceSum(local);
    __shared__ float part[16];
    const int wave = tid >> 6, lane = tid & 63;
    if (lane == 0) part[wave] = local;
    __syncthreads();
    if (tid == 0) {
        float s = 0.0f;
        for (int i = 0; i < 16; ++i) s += part[i];
        out[NPRED] = s;
    }
}

extern "C" void kernel_launch(void* const* d_in, const int* in_sizes, int n_in,
                              void* d_out, int out_size, void* d_ws, size_t ws_size,
                              hipStream_t stream)
{
    const float* uEmbed  = (const float*)d_in[0];
    const float* iEmbed  = (const float*)d_in[1];
    const float* posEmbed= (const float*)d_in[2];
    const float* Wih     = (const float*)d_in[3];
    const float* Whh     = (const float*)d_in[4];
    const float* bih     = (const float*)d_in[5];
    const float* bhh     = (const float*)d_in[6];
    const float* Wq0     = (const float*)d_in[7];
    const float* Wk0     = (const float*)d_in[8];
    const float* Wv0     = (const float*)d_in[9];
    const float* Wq1     = (const float*)d_in[10];
    const float* Wk1     = (const float*)d_in[11];
    const float* Wv1     = (const float*)d_in[12];
    const float* Wv_seq  = (const float*)d_in[15];
    const float* meta2_W = (const float*)d_in[16];
    const float* meta2_b = (const float*)d_in[17];
    const float* meta3_W = (const float*)d_in[18];
    const float* meta3_b = (const float*)d_in[19];
    const float* mask    = (const float*)d_in[20];
    const int*   uids    = (const int*)d_in[21];
    const int*   iids    = (const int*)d_in[22];
    const int*   sequence= (const int*)d_in[23];
    const int*   uLocs   = (const int*)d_in[24];
    const int*   suids   = (const int*)d_in[25];
    const int*   siids   = (const int*)d_in[26];

    char*  wsB      = (char*)d_ws;
    char*  fragtab  = wsB;                                 // 112KB frags
    float* biastab  = (float*)(wsB + 116 * 1024);          // 1KB bias
    float* finalv   = (float*)(wsB + 128 * 1024);          // N_ROWS*64
    float* att_user = finalv + (size_t)N_ROWS * D_DIM;     // B*64
    float* uwB      = att_user + (size_t)B_CNT * D_DIM;    // G*NS
    float* SfB      = uwB + (size_t)G_CNT * NS_CNT;
    float* p1B      = SfB + (size_t)G_CNT * NS_CNT;
    float* out      = (float*)d_out;

    prep_kernel<<<1, 512, 0, stream>>>(
        Wih, Whh, bih, bhh, Wq0, Wk0, Wv0, Wq1, Wk1, Wv1, fragtab, biastab);

    tower_kernel<<<(N_ROWS + 127) / 128, 512, 0, stream>>>(
        uEmbed, iEmbed, fragtab, biastab, finalv);

    seq_att_kernel<<<(B_CNT + 3) / 4, 256, 0, stream>>>(
        finalv, posEmbed, mask, sequence, Wv_seq, att_user);

    pergs_kernel<<<(G_CNT * NS_CNT) / 4, 256, 0, stream>>>(
        finalv, uEmbed, iEmbed, suids, siids, meta2_W, meta2_b, meta3_W, meta3_b,
        uwB, SfB, p1B);

    preds_kernel<<<NPRED / 4, 256, 0, stream>>>(finalv, att_user, uids, iids, uLocs, out);

    ssl_kernel<<<1, 1024, 0, stream>>>(uwB, SfB, p1B, out);
}